// Round 1
// baseline (2095.395 us; speedup 1.0000x reference)
//
#include <hip/hip_runtime.h>
#include <hip/hip_bf16.h>
#include <math.h>

// Shapes (fixed by the reference)
#define Bn 16
#define Sn 64
#define Tn 64
#define En 256
#define Hn 512
#define VS 32000
#define Jn 201
#define Mn 100

// Workspace layout (float offsets)
#define O_HCAT   0                         // [1024][1024] = 1048576
#define O_HSTATE 1048576                   // [2 buf][2 dir][16][512] = 32768
#define O_CSTATE 1081344                   // [2][16][512] = 16384
#define O_DENOM  1097728                   // [1024]
#define O_NULLD  1098752                   // [64]
#define ZERO_N   1098816                   // floats to zero (all of the above)
#define O_NS     1098816                   // [512]
#define O_GX     1099328                   // [2][1024][2048] = 4194304
#define O_TS     5293632                   // [1024][512]
#define O_TTPRE  5817920                   // [1024][256]
#define O_TT     6080064                   // [1024][512]

__device__ __forceinline__ float sigf(float x) { return 1.0f / (1.0f + expf(-x)); }

// ---------------- zero workspace ----------------
__global__ void zero_k(float4* __restrict__ p, int n4) {
    int i = blockIdx.x * blockDim.x + threadIdx.x;
    if (i < n4) p[i] = make_float4(0.f, 0.f, 0.f, 0.f);
}

// ---------------- generic tiled GEMM: C = act(A@B + bias) ----------------
// A [M,K] row-major (optional row gather: row r -> A + idx[r]*K), B [K,N] row-major.
// BM=BN=64, BK=16, 256 threads, 4x4 register tile. M%64==0, N%64==0, K%16==0.
template <int ACT>
__global__ __launch_bounds__(256) void gemm_k(const float* __restrict__ A,
                                              const float* __restrict__ B,
                                              const float* __restrict__ bias,
                                              float* __restrict__ C,
                                              int M, int N, int K,
                                              const int* __restrict__ gidx) {
    __shared__ float As[16][68];
    __shared__ float Bs[16][68];
    int tid = threadIdx.x;
    int bm = blockIdx.y * 64, bn = blockIdx.x * 64;
    int tm = tid >> 4, tn = tid & 15;
    int ar = tid >> 2, akq = (tid & 3) * 4;
    int bk = tid >> 4, bn4 = (tid & 15) * 4;
    float acc[4][4] = {};
    for (int k0 = 0; k0 < K; k0 += 16) {
        int grow = bm + ar;
        const float* arow = gidx ? (A + (size_t)gidx[grow] * K) : (A + (size_t)grow * K);
        float4 av = *(const float4*)(arow + k0 + akq);
        As[akq + 0][ar] = av.x; As[akq + 1][ar] = av.y;
        As[akq + 2][ar] = av.z; As[akq + 3][ar] = av.w;
        *(float4*)&Bs[bk][bn4] = *(const float4*)(B + (size_t)(k0 + bk) * N + bn + bn4);
        __syncthreads();
#pragma unroll
        for (int kk = 0; kk < 16; ++kk) {
            float a[4], bb[4];
#pragma unroll
            for (int i = 0; i < 4; i++) a[i] = As[kk][tm * 4 + i];
#pragma unroll
            for (int j = 0; j < 4; j++) bb[j] = Bs[kk][tn * 4 + j];
#pragma unroll
            for (int i = 0; i < 4; i++)
#pragma unroll
                for (int j = 0; j < 4; j++) acc[i][j] += a[i] * bb[j];
        }
        __syncthreads();
    }
#pragma unroll
    for (int i = 0; i < 4; i++) {
        int row = bm + tm * 4 + i;
        float4 o;
        float v[4];
#pragma unroll
        for (int j = 0; j < 4; j++) {
            float x = acc[i][j] + (bias ? bias[bn + tn * 4 + j] : 0.f);
            if (ACT == 1) x = tanhf(x);
            v[j] = x;
        }
        o.x = v[0]; o.y = v[1]; o.z = v[2]; o.w = v[3];
        *(float4*)&C[(size_t)row * N + bn + tn * 4] = o;
    }
}

// ---------------- null state: ns = tanh(emb[tnull] @ nnW + nnb) ----------------
__global__ __launch_bounds__(256) void null_state_k(const float* __restrict__ emb,
                                                    const int* __restrict__ tnull,
                                                    const float* __restrict__ nnW,
                                                    const float* __restrict__ nnb,
                                                    float* __restrict__ ns) {
    __shared__ float xn[En];
    int t = threadIdx.x;
    xn[t] = emb[(size_t)tnull[0] * En + t];
    __syncthreads();
    for (int h = t; h < Hn; h += 256) {
        float a = nnb[h];
        for (int e = 0; e < En; e++) a += xn[e] * nnW[(size_t)e * Hn + h];
        ns[h] = tanhf(a);
    }
}

// ---------------- null denom: sum_v exp(ns . Wv[:,v] + bv[v]) ----------------
__global__ __launch_bounds__(256) void null_denom_k(const float* __restrict__ ns,
                                                    const float* __restrict__ Wv,
                                                    const float* __restrict__ bv,
                                                    float* __restrict__ nd) {
    __shared__ float nsl[Hn];
    __shared__ float red[4];
    int t = threadIdx.x;
    int v = blockIdx.x * 256 + t;
    nsl[t] = ns[t];
    nsl[t + 256] = ns[t + 256];
    __syncthreads();
    float a = bv[v];
    for (int k = 0; k < Hn; k++) a += nsl[k] * Wv[(size_t)k * VS + v];
    float e = expf(a);
    for (int o = 1; o < 64; o <<= 1) e += __shfl_xor(e, o);
    if ((t & 63) == 0) red[t >> 6] = e;
    __syncthreads();
    if (t == 0) atomicAdd(nd, red[0] + red[1] + red[2] + red[3]);
}

// ---------------- LSTM one step (both directions) ----------------
// 256 blocks: dir = blk>>7, 4 hidden units per block. 256 threads.
__global__ __launch_bounds__(256) void lstm_step_k(int s,
                                                   const float* __restrict__ wh_fw,
                                                   const float* __restrict__ wh_bw,
                                                   const float* __restrict__ gx,
                                                   const int* __restrict__ lengths,
                                                   const float* __restrict__ h_read,
                                                   float* __restrict__ h_write,
                                                   float* __restrict__ cstate,
                                                   float* __restrict__ hcat) {
    __shared__ float wbuf[512][20];  // [k][16 cols], padded stride vs bank conflicts
    __shared__ float red[4][16][16];
    int blk = blockIdx.x;
    int dir = blk >> 7;
    int cb = blk & 127;
    int u0 = cb * 4;
    int tid = threadIdx.x;
    const float* wh = dir ? wh_bw : wh_fw;
    {
        int grp = tid & 3;       // gate
        int kb = tid >> 2;       // 0..63
#pragma unroll
        for (int it = 0; it < 8; ++it) {
            int k = kb + it * 64;
            float4 w = *(const float4*)(wh + (size_t)k * 2048 + grp * 512 + u0);
            *(float4*)&wbuf[k][grp * 4] = w;
        }
    }
    __syncthreads();
    int vg = tid & 3, bg = (tid >> 2) & 3, ks = tid >> 4;
    int c0 = vg * 4, b0 = bg * 4;
    const float* hr = h_read + dir * 8192;
    float acc[4][4] = {};
#pragma unroll
    for (int it = 0; it < 8; ++it) {
        int k4 = ks * 8 + it;  // float4 index into K
        float hv[4][4], wv4[4][4];
#pragma unroll
        for (int i = 0; i < 4; i++) {
            float4 h4 = *(const float4*)(hr + (b0 + i) * 512 + k4 * 4);
            hv[i][0] = h4.x; hv[i][1] = h4.y; hv[i][2] = h4.z; hv[i][3] = h4.w;
        }
#pragma unroll
        for (int kk = 0; kk < 4; kk++) {
            float4 w4 = *(const float4*)&wbuf[k4 * 4 + kk][c0];
            wv4[kk][0] = w4.x; wv4[kk][1] = w4.y; wv4[kk][2] = w4.z; wv4[kk][3] = w4.w;
        }
#pragma unroll
        for (int i = 0; i < 4; i++)
#pragma unroll
            for (int kk = 0; kk < 4; kk++)
#pragma unroll
                for (int j = 0; j < 4; j++) acc[i][j] += hv[i][kk] * wv4[kk][j];
    }
#pragma unroll
    for (int i = 0; i < 4; i++)
#pragma unroll
        for (int j = 0; j < 4; j++) {
            acc[i][j] += __shfl_xor(acc[i][j], 32);
            acc[i][j] += __shfl_xor(acc[i][j], 16);
        }
    if ((tid & 48) == 0) {  // lanes 0..15 of each wave hold the wave's ks-sum
        int w = tid >> 6;
#pragma unroll
        for (int i = 0; i < 4; i++)
#pragma unroll
            for (int j = 0; j < 4; j++) red[w][b0 + i][c0 + j] = acc[i][j];
    }
    __syncthreads();
    if (tid < 64) {
        int b = tid >> 2, uoff = tid & 3;
        int u = u0 + uoff;
        int len = lengths[b];
        if (s < len) {
            int tin = dir ? (len - 1 - s) : s;
            const float* gxr = gx + (size_t)dir * 2097152 + (size_t)(b * 64 + tin) * 2048;
            float g[4];
#pragma unroll
            for (int gate = 0; gate < 4; ++gate) {
                int c = gate * 4 + uoff;
                g[gate] = red[0][b][c] + red[1][b][c] + red[2][b][c] + red[3][b][c] +
                          gxr[gate * 512 + u0 + uoff];
            }
            float* cp = cstate + dir * 8192 + b * 512 + u;
            float co = *cp;
            float cn = sigf(g[2] + 1.0f) * co + sigf(g[0]) * tanhf(g[1]);
            float hn = sigf(g[3]) * tanhf(cn);
            *cp = cn;
            h_write[dir * 8192 + b * 512 + u] = hn;
            hcat[(size_t)(b * 64 + tin) * 1024 + dir * 512 + u] = hn;
        } else {
            // frozen: carry h forward into the other ping-pong buffer
            h_write[dir * 8192 + b * 512 + u] = h_read[dir * 8192 + b * 512 + u];
        }
    }
}

// ---------------- Phase A: denom[bt] = sum_v exp(ts[bt].Wv[:,v] + bv[v]) ----------------
// 1000 blocks x 32 v-cols; Wv tile in 64KB LDS; 4x4 register tiles; shuffle reduce + atomicAdd.
__global__ __launch_bounds__(256) void phaseA_k(const float* __restrict__ ts,
                                                const float* __restrict__ Wv,
                                                const float* __restrict__ bv,
                                                float* __restrict__ denom) {
    __shared__ float wv[512][32];
    int v0 = blockIdx.x * 32;
    int tid = threadIdx.x;
    {
        int c4 = (tid & 7) * 4, kb = tid >> 3;
#pragma unroll
        for (int it = 0; it < 16; ++it) {
            int k = kb + it * 32;
            *(float4*)&wv[k][c4] = *(const float4*)(Wv + (size_t)k * VS + v0 + c4);
        }
    }
    __syncthreads();
    int vg = tid & 7, rg = tid >> 3;
    int c0 = vg * 4;
    float bvv[4];
#pragma unroll
    for (int j = 0; j < 4; j++) bvv[j] = bv[v0 + c0 + j];
    for (int chunk = 0; chunk < 8; ++chunk) {
        int r0 = chunk * 128 + rg * 4;
        float acc[4][4] = {};
        for (int k4 = 0; k4 < 128; ++k4) {
            float tv[4][4], wr[4][4];
#pragma unroll
            for (int i = 0; i < 4; i++) {
                float4 t4 = *(const float4*)(ts + (size_t)(r0 + i) * 512 + k4 * 4);
                tv[i][0] = t4.x; tv[i][1] = t4.y; tv[i][2] = t4.z; tv[i][3] = t4.w;
            }
#pragma unroll
            for (int kk = 0; kk < 4; kk++) {
                float4 w4 = *(const float4*)&wv[k4 * 4 + kk][c0];
                wr[kk][0] = w4.x; wr[kk][1] = w4.y; wr[kk][2] = w4.z; wr[kk][3] = w4.w;
            }
#pragma unroll
            for (int i = 0; i < 4; i++)
#pragma unroll
                for (int kk = 0; kk < 4; kk++)
#pragma unroll
                    for (int j = 0; j < 4; j++) acc[i][j] += tv[i][kk] * wr[kk][j];
        }
#pragma unroll
        for (int i = 0; i < 4; i++) {
            float srow = expf(acc[i][0] + bvv[0]) + expf(acc[i][1] + bvv[1]) +
                         expf(acc[i][2] + bvv[2]) + expf(acc[i][3] + bvv[3]);
            srow += __shfl_xor(srow, 1);
            srow += __shfl_xor(srow, 2);
            srow += __shfl_xor(srow, 4);
            if (vg == 0) atomicAdd(&denom[r0 + i], srow);
        }
    }
}

// ---------------- emission assembly ----------------
// grid (8 s-chunks, 16 b); 512 threads.
__global__ __launch_bounds__(512) void emission_k(const float* __restrict__ ts,
                                                  const float* __restrict__ Wv,
                                                  const float* __restrict__ bv,
                                                  const int* __restrict__ sources,
                                                  const float* __restrict__ ns,
                                                  const float* __restrict__ denom,
                                                  const float* __restrict__ nulld,
                                                  float* __restrict__ em) {
    __shared__ float colv[512];
    __shared__ float red[64][9];
    __shared__ float red2[8];
    __shared__ float env_s, bvc_s;
    int b = blockIdx.y, sc = blockIdx.x;
    int tid = threadIdx.x;
    for (int q = 0; q < 8; ++q) {
        int s = sc * 8 + q;
        int c = sources[b * 64 + s];
        __syncthreads();
        colv[tid] = Wv[(size_t)tid * VS + c];
        if (tid == 0) bvc_s = bv[c];
        __syncthreads();
        int r = tid & 63, ksl = tid >> 6;
        const float* tr = ts + (size_t)(b * 64 + r) * 512 + ksl * 64;
        float p = 0.f;
#pragma unroll
        for (int k4 = 0; k4 < 16; k4++) {
            float4 t4 = *(const float4*)(tr + k4 * 4);
            float4 c4 = *(const float4*)&colv[ksl * 64 + k4 * 4];
            p += t4.x * c4.x + t4.y * c4.y + t4.z * c4.z + t4.w * c4.w;
        }
        red[r][ksl] = p;
        if (tid < 8) {
            float pn = 0.f;
#pragma unroll
            for (int k4 = 0; k4 < 16; k4++) {
                float4 n4 = *(const float4*)(ns + tid * 64 + k4 * 4);
                float4 c4 = *(const float4*)&colv[tid * 64 + k4 * 4];
                pn += n4.x * c4.x + n4.y * c4.y + n4.z * c4.z + n4.w * c4.w;
            }
            red2[tid] = pn;
        }
        __syncthreads();
        if (tid < 64) {
            float dot = red[tid][0] + red[tid][1] + red[tid][2] + red[tid][3] +
                        red[tid][4] + red[tid][5] + red[tid][6] + red[tid][7];
            float ew = expf(dot + bvc_s) / denom[b * 64 + tid];
            em[(size_t)(b * 128 + tid) * 64 + s] = ew;
        } else if (tid == 64) {
            float dn = red2[0] + red2[1] + red2[2] + red2[3] +
                       red2[4] + red2[5] + red2[6] + red2[7];
            env_s = expf(dn + bvc_s) / nulld[0];
        }
        __syncthreads();
        if (tid < 64) em[(size_t)(b * 128 + 64 + tid) * 64 + s] = env_s;
    }
}

// ---------------- transition: jump softmax + p0, assemble both outputs ----------------
// 1024 blocks = (b, i); 256 threads.
__global__ __launch_bounds__(256) void transition_k(const float* __restrict__ tt,
                                                    const float* __restrict__ Wj,
                                                    const float* __restrict__ bj,
                                                    const float* __restrict__ Wp0,
                                                    const float* __restrict__ bp0,
                                                    float* __restrict__ trans,
                                                    float* __restrict__ tlog) {
    __shared__ float ttl[512];
    __shared__ float jrow[Jn], ljrow[Jn];
    __shared__ float sred[256];
    __shared__ float p0_s, lp0_s;
    int blk = blockIdx.x;
    int b = blk >> 6, i = blk & 63;
    int tid = threadIdx.x;
    {
        const float* trr = tt + (size_t)blk * 512;
        if (tid < 128) *(float4*)&ttl[tid * 4] = *(const float4*)(trr + tid * 4);
    }
    __syncthreads();
    bool isj = tid < Jn;
    bool isp = tid == Jn;
    float l = 0.f;
    if (isj || isp) {
        const float* wb = isj ? (Wj + tid) : Wp0;
        int stride = isj ? Jn : 1;
        float a = isj ? bj[tid] : bp0[0];
        for (int k = 0; k < 512; k++) a += ttl[k] * wb[(size_t)k * stride];
        l = a;
    }
    sred[tid] = isj ? l : -1e30f;
    __syncthreads();
    for (int o = 128; o > 0; o >>= 1) {
        if (tid < o) sred[tid] = fmaxf(sred[tid], sred[tid + o]);
        __syncthreads();
    }
    float m = sred[0];
    __syncthreads();
    float ex = isj ? expf(l - m) : 0.f;
    sred[tid] = ex;
    __syncthreads();
    for (int o = 128; o > 0; o >>= 1) {
        if (tid < o) sred[tid] += sred[tid + o];
        __syncthreads();
    }
    float S = sred[0];
    if (isj) {
        jrow[tid] = ex / S;
        ljrow[tid] = (l - m) - logf(S);
    }
    if (isp) {
        float pv = 1.f / (1.f + expf(-l));
        p0_s = pv;
        lp0_s = logf(pv);
    }
    __syncthreads();
    if (tid < 128) {
        int j = tid;
        float tv, lv;
        if (j < 64) {
            int id = Mn + j - i;  // in [37,163]
            tv = jrow[id];
            lv = ljrow[id];
        } else {
            bool dg = (j - 64) == i;
            tv = dg ? p0_s : 0.f;
            lv = dg ? lp0_s : 0.f;
        }
        size_t r1 = (size_t)(b * 128 + i) * 128 + j;
        size_t r2 = (size_t)(b * 128 + 64 + i) * 128 + j;
        trans[r1] = tv;
        trans[r2] = tv;
        tlog[r1] = lv;
        tlog[r2] = lv;
    }
}

extern "C" void kernel_launch(void* const* d_in, const int* in_sizes, int n_in,
                              void* d_out, int out_size, void* d_ws, size_t ws_size,
                              hipStream_t stream) {
    const int* sources = (const int*)d_in[0];
    const int* targets = (const int*)d_in[1];
    const int* tnull = (const int*)d_in[2];
    const int* lengths = (const int*)d_in[3];
    const float* emb = (const float*)d_in[4];
    const float* nnW = (const float*)d_in[5];
    const float* nnb = (const float*)d_in[6];
    const float* Wx_fw = (const float*)d_in[7];
    const float* Wh_fw = (const float*)d_in[8];
    const float* b_fw = (const float*)d_in[9];
    const float* Wx_bw = (const float*)d_in[10];
    const float* Wh_bw = (const float*)d_in[11];
    const float* b_bw = (const float*)d_in[12];
    const float* Wproj_e = (const float*)d_in[13];
    const float* Wv = (const float*)d_in[14];
    const float* bv = (const float*)d_in[15];
    const float* Wproj_t = (const float*)d_in[16];
    const float* Wj = (const float*)d_in[17];
    const float* bj = (const float*)d_in[18];
    const float* Wp0 = (const float*)d_in[19];
    const float* bp0 = (const float*)d_in[20];

    float* ws = (float*)d_ws;
    float* out = (float*)d_out;
    float* out_em = out;                       // [16][128][64]
    float* out_tr = out + 131072;              // [16][128][128]
    float* out_tl = out + 131072 + 262144;     // [16][128][128]

    // 1) zero state/accumulator regions
    zero_k<<<1074, 256, 0, stream>>>((float4*)ws, ZERO_N / 4);

    // 2) gx = gather(emb, targets) @ Wx + b  (both directions)
    dim3 g1(2048 / 64, 1024 / 64);
    gemm_k<0><<<g1, 256, 0, stream>>>(emb, Wx_fw, b_fw, ws + O_GX, 1024, 2048, 256, targets);
    gemm_k<0><<<g1, 256, 0, stream>>>(emb, Wx_bw, b_bw, ws + O_GX + 2097152, 1024, 2048, 256, targets);

    // 3) null state + its softmax denominator
    null_state_k<<<1, 256, 0, stream>>>(emb, tnull, nnW, nnb, ws + O_NS);
    null_denom_k<<<125, 256, 0, stream>>>(ws + O_NS, Wv, bv, ws + O_NULLD);

    // 4) LSTM recurrence (fw+bw), ping-pong h buffers
    for (int s = 0; s < Tn; ++s) {
        lstm_step_k<<<256, 256, 0, stream>>>(s, Wh_fw, Wh_bw, ws + O_GX, lengths,
                                             ws + O_HSTATE + (s & 1) * 16384,
                                             ws + O_HSTATE + ((s + 1) & 1) * 16384,
                                             ws + O_CSTATE, ws + O_HCAT);
    }

    // 5) projections
    gemm_k<0><<<dim3(512 / 64, 16), 256, 0, stream>>>(ws + O_HCAT, Wproj_e, nullptr,
                                                      ws + O_TS, 1024, 512, 1024, nullptr);
    gemm_k<0><<<dim3(256 / 64, 16), 256, 0, stream>>>(ws + O_HCAT, Wproj_t, nullptr,
                                                      ws + O_TTPRE, 1024, 256, 1024, nullptr);
    gemm_k<1><<<dim3(512 / 64, 16), 256, 0, stream>>>(ws + O_TTPRE, nnW, nnb,
                                                      ws + O_TT, 1024, 512, 256, nullptr);

    // 6) emission softmax denominators over Vs=32000
    phaseA_k<<<1000, 256, 0, stream>>>(ws + O_TS, Wv, bv, ws + O_DENOM);

    // 7) emission output
    emission_k<<<dim3(8, 16), 512, 0, stream>>>(ws + O_TS, Wv, bv, sources, ws + O_NS,
                                                ws + O_DENOM, ws + O_NULLD, out_em);

    // 8) transition outputs
    transition_k<<<1024, 256, 0, stream>>>(ws + O_TT, Wj, bj, Wp0, bp0, out_tr, out_tl);
}

// Round 2
// 1800.552 us; speedup vs baseline: 1.1638x; 1.1638x over previous
//
#include <hip/hip_runtime.h>
#include <hip/hip_bf16.h>
#include <math.h>

// Shapes (fixed by the reference)
#define Bn 16
#define Sn 64
#define Tn 64
#define En 256
#define Hn 512
#define VS 32000
#define Jn 201
#define Mn 100

// Workspace layout (float offsets)
#define O_HCAT   0                      // [1024][1024]
#define O_DENOM  1048576                // [1024]
#define O_NULLD  1049600                // [64]
#define O_BAR    1049664                // [16] uint barrier counters
#define ZERO_N   1049680
#define O_NS     1049680                // [512]
#define O_H      1050192                // [2 buf][2 dir][512 u][16 b] = 32768
#define O_TS     1082960                // [1024][512] fp32
#define O_TSB    1607248                // ts bf16 swizzled: 524288 bf16 = 262144 floats
#define O_TT     1869392                // [1024][512]
#define O_TTPRE  2393680                // [1024][256]
#define O_WVB    2655824                // Wv bf16 swizzled: 2000*16*64*8 bf16 = 8192000 floats
#define O_GX     2655824                // [2][1024][2048] = 4194304 (overlaps WVB; gx dead before conversion)

typedef __attribute__((ext_vector_type(8))) short short8;
typedef __attribute__((ext_vector_type(4))) float f32x4;

__device__ __forceinline__ float sigf(float x) { return 1.0f / (1.0f + expf(-x)); }
__device__ __forceinline__ unsigned short tobf(float x) {
    __hip_bfloat16 h = __float2bfloat16(x);
    return *reinterpret_cast<unsigned short*>(&h);
}

// ---------------- zero workspace ----------------
__global__ void zero_k(float4* __restrict__ p, int n4) {
    int i = blockIdx.x * blockDim.x + threadIdx.x;
    if (i < n4) p[i] = make_float4(0.f, 0.f, 0.f, 0.f);
}

// ---------------- generic tiled GEMM: C = act(A@B + bias) ----------------
template <int ACT>
__global__ __launch_bounds__(256) void gemm_k(const float* __restrict__ A,
                                              const float* __restrict__ B,
                                              const float* __restrict__ bias,
                                              float* __restrict__ C,
                                              int M, int N, int K,
                                              const int* __restrict__ gidx) {
    __shared__ float As[16][68];
    __shared__ float Bs[16][68];
    int tid = threadIdx.x;
    int bm = blockIdx.y * 64, bn = blockIdx.x * 64;
    int tm = tid >> 4, tn = tid & 15;
    int ar = tid >> 2, akq = (tid & 3) * 4;
    int bk = tid >> 4, bn4 = (tid & 15) * 4;
    float acc[4][4] = {};
    for (int k0 = 0; k0 < K; k0 += 16) {
        int grow = bm + ar;
        const float* arow = gidx ? (A + (size_t)gidx[grow] * K) : (A + (size_t)grow * K);
        float4 av = *(const float4*)(arow + k0 + akq);
        As[akq + 0][ar] = av.x; As[akq + 1][ar] = av.y;
        As[akq + 2][ar] = av.z; As[akq + 3][ar] = av.w;
        *(float4*)&Bs[bk][bn4] = *(const float4*)(B + (size_t)(k0 + bk) * N + bn + bn4);
        __syncthreads();
#pragma unroll
        for (int kk = 0; kk < 16; ++kk) {
            float a[4], bb[4];
#pragma unroll
            for (int i = 0; i < 4; i++) a[i] = As[kk][tm * 4 + i];
#pragma unroll
            for (int j = 0; j < 4; j++) bb[j] = Bs[kk][tn * 4 + j];
#pragma unroll
            for (int i = 0; i < 4; i++)
#pragma unroll
                for (int j = 0; j < 4; j++) acc[i][j] += a[i] * bb[j];
        }
        __syncthreads();
    }
#pragma unroll
    for (int i = 0; i < 4; i++) {
        int row = bm + tm * 4 + i;
        float4 o;
        float v[4];
#pragma unroll
        for (int j = 0; j < 4; j++) {
            float x = acc[i][j] + (bias ? bias[bn + tn * 4 + j] : 0.f);
            if (ACT == 1) x = tanhf(x);
            v[j] = x;
        }
        o.x = v[0]; o.y = v[1]; o.z = v[2]; o.w = v[3];
        *(float4*)&C[(size_t)row * N + bn + tn * 4] = o;
    }
}

// ---------------- null state ----------------
__global__ __launch_bounds__(256) void null_state_k(const float* __restrict__ emb,
                                                    const int* __restrict__ tnull,
                                                    const float* __restrict__ nnW,
                                                    const float* __restrict__ nnb,
                                                    float* __restrict__ ns) {
    __shared__ float xn[En];
    int t = threadIdx.x;
    xn[t] = emb[(size_t)tnull[0] * En + t];
    __syncthreads();
    for (int h = t; h < Hn; h += 256) {
        float a = nnb[h];
        for (int e = 0; e < En; e++) a += xn[e] * nnW[(size_t)e * Hn + h];
        ns[h] = tanhf(a);
    }
}

// ---------------- null denom ----------------
__global__ __launch_bounds__(256) void null_denom_k(const float* __restrict__ ns,
                                                    const float* __restrict__ Wv,
                                                    const float* __restrict__ bv,
                                                    float* __restrict__ nd) {
    __shared__ float nsl[Hn];
    __shared__ float red[4];
    int t = threadIdx.x;
    int v = blockIdx.x * 256 + t;
    nsl[t] = ns[t];
    nsl[t + 256] = ns[t + 256];
    __syncthreads();
    float a = bv[v];
    for (int k = 0; k < Hn; k++) a += nsl[k] * Wv[(size_t)k * VS + v];
    float e = expf(a);
    for (int o = 1; o < 64; o <<= 1) e += __shfl_xor(e, o);
    if ((t & 63) == 0) red[t >> 6] = e;
    __syncthreads();
    if (t == 0) atomicAdd(nd, red[0] + red[1] + red[2] + red[3]);
}

// ---------------- persistent bidirectional LSTM ----------------
// 128 blocks x 512 threads. Block: dir=blk>>6, 8 units (u0=(blk&63)*8) x 4 gates.
// Wh slice resident in LDS for all 64 steps; h exchanged via global ping-pong +
// two-level grid barrier (agent-scope atomics + threadfence for cross-XCD coherence).
__global__ __launch_bounds__(512, 1) void lstm_persist_k(const float* __restrict__ wh_fw,
                                                         const float* __restrict__ wh_bw,
                                                         const float* __restrict__ gx,
                                                         const int* __restrict__ lengths,
                                                         float* __restrict__ hglob,
                                                         float* __restrict__ hcat,
                                                         unsigned* __restrict__ bar) {
    __shared__ float wbuf[512][32];    // [k][g*8+uu]
    __shared__ float hbufT[512][16];   // [u][b]
    __shared__ float red[8][32][16];
    __shared__ float gbuf[16][32];
    __shared__ float cbuf[16][8];
    __shared__ int lenS[16];
    int tid = threadIdx.x;
    int blk = blockIdx.x;
    int dir = blk >> 6;
    int u0 = (blk & 63) * 8;
    const float* wh = dir ? wh_bw : wh_fw;
    {
        int k = tid;
#pragma unroll
        for (int g = 0; g < 4; g++) {
            float4 w0 = *(const float4*)(wh + (size_t)k * 2048 + g * 512 + u0);
            float4 w1 = *(const float4*)(wh + (size_t)k * 2048 + g * 512 + u0 + 4);
            *(float4*)&wbuf[k][g * 8] = w0;
            *(float4*)&wbuf[k][g * 8 + 4] = w1;
        }
    }
    if (tid < 16) lenS[tid] = lengths[tid];
    {   // zero hbufT (h_init = 0) and cbuf
        float4 z = make_float4(0.f, 0.f, 0.f, 0.f);
        float* hb = &hbufT[0][0];
#pragma unroll
        for (int q = 0; q < 4; q++) *(float4*)(hb + tid * 16 + q * 4) = z;
        if (tid < 128) (&cbuf[0][0])[tid] = 0.f;
    }
    __syncthreads();

    int ks = tid >> 5, r = tid & 31, bq = r >> 3, cq = r & 7;
    int c0 = cq * 4, b0 = bq * 4;
    int wv_ = tid >> 6;

    for (int s = 0; s < 64; ++s) {
        // ---- gate matvec: acc[ci][bi] over K-slice ----
        float acc[4][4] = {};
        int kbase = ks * 32;
#pragma unroll 8
        for (int k = 0; k < 32; k++) {
            float4 w4 = *(float4*)&wbuf[kbase + k][c0];
            float4 h4 = *(float4*)&hbufT[kbase + k][b0];
            float wa[4] = {w4.x, w4.y, w4.z, w4.w};
            float ha[4] = {h4.x, h4.y, h4.z, h4.w};
#pragma unroll
            for (int ci = 0; ci < 4; ci++)
#pragma unroll
                for (int bi = 0; bi < 4; bi++) acc[ci][bi] += wa[ci] * ha[bi];
        }
#pragma unroll
        for (int ci = 0; ci < 4; ci++)
#pragma unroll
            for (int bi = 0; bi < 4; bi++) acc[ci][bi] += __shfl_xor(acc[ci][bi], 32);
        if ((tid & 63) < 32) {
#pragma unroll
            for (int ci = 0; ci < 4; ci++)
#pragma unroll
                for (int bi = 0; bi < 4; bi++) red[wv_][r][ci * 4 + bi] = acc[ci][bi];
        }
        __syncthreads();
        {   // combine 8 wave-partials -> gbuf[b][c]
            int b = tid >> 5, c = tid & 31;
            int rr = (b >> 2) * 8 + (c >> 2);
            int idx = (c & 3) * 4 + (b & 3);
            float pre = 0.f;
#pragma unroll
            for (int w = 0; w < 8; w++) pre += red[w][rr][idx];
            gbuf[b][c] = pre;
        }
        __syncthreads();
        if (tid < 128) {
            int b = tid >> 3, uu = tid & 7;
            int len = lenS[b];
            float hn;
            if (s < len) {
                int tin = dir ? (len - 1 - s) : s;
                const float* gxr = gx + (size_t)dir * 2097152 + (size_t)(b * 64 + tin) * 2048 + u0 + uu;
                float gi = gbuf[b][uu] + gxr[0];
                float gj = gbuf[b][8 + uu] + gxr[512];
                float gf = gbuf[b][16 + uu] + gxr[1024];
                float go = gbuf[b][24 + uu] + gxr[1536];
                float co = cbuf[b][uu];
                float cn = sigf(gf + 1.0f) * co + sigf(gi) * tanhf(gj);
                hn = sigf(go) * tanhf(cn);
                cbuf[b][uu] = cn;
                hcat[(size_t)(b * 64 + tin) * 1024 + dir * 512 + u0 + uu] = hn;
            } else {
                hn = hbufT[u0 + uu][b];  // frozen: carry forward
            }
            hglob[((s + 1) & 1) * 16384 + dir * 8192 + (u0 + uu) * 16 + b] = hn;
        }
        if (s == 63) break;
        __syncthreads();  // drains vmem (compiler emits vmcnt(0) before s_barrier)
        if (tid == 0) {
            __threadfence();  // release: publish this block's h stores (wbl2)
            unsigned o = __hip_atomic_fetch_add(&bar[blk & 7], 1u, __ATOMIC_ACQ_REL,
                                                __HIP_MEMORY_SCOPE_AGENT);
            if (o == (unsigned)(s * 16 + 15)) {
                unsigned o2 = __hip_atomic_fetch_add(&bar[8], 1u, __ATOMIC_ACQ_REL,
                                                     __HIP_MEMORY_SCOPE_AGENT);
                if (o2 == (unsigned)(s * 8 + 7)) {
                    __hip_atomic_store(&bar[9], (unsigned)(s + 1), __ATOMIC_RELEASE,
                                       __HIP_MEMORY_SCOPE_AGENT);
                }
            }
            while (__hip_atomic_load(&bar[9], __ATOMIC_ACQUIRE, __HIP_MEMORY_SCOPE_AGENT) <
                   (unsigned)(s + 1)) {
                __builtin_amdgcn_s_sleep(8);
            }
            __threadfence();  // acquire: invalidate L1/L2 (inv)
        }
        __syncthreads();
        {   // restage next h (flat [u][b] copy, coalesced)
            const float* hsrc = hglob + ((s + 1) & 1) * 16384 + dir * 8192;
            float* hb = &hbufT[0][0];
#pragma unroll
            for (int q = 0; q < 4; q++)
                *(float4*)(hb + tid * 16 + q * 4) = *(const float4*)(hsrc + tid * 16 + q * 4);
        }
        __syncthreads();
    }
}

// ---------------- bf16 fragment-swizzle conversions ----------------
// tsb[mt][ks][lane][j] = ts[mt*16 + (lane&15)][ks*32 + (lane>>4)*8 + j]
__global__ __launch_bounds__(256) void convert_ts_k(const float* __restrict__ ts,
                                                    uint4* __restrict__ tsb) {
    int g = blockIdx.x * 256 + threadIdx.x;  // 65536
    int l = g & 63, ks = (g >> 6) & 15, mt = g >> 10;
    int m = mt * 16 + (l & 15);
    int k0 = ks * 32 + (l >> 4) * 8;
    const float* p = ts + (size_t)m * 512 + k0;
    float4 f0 = *(const float4*)(p);
    float4 f1 = *(const float4*)(p + 4);
    unsigned short u[8] = {tobf(f0.x), tobf(f0.y), tobf(f0.z), tobf(f0.w),
                           tobf(f1.x), tobf(f1.y), tobf(f1.z), tobf(f1.w)};
    tsb[g] = *(uint4*)u;
}

// wvb[nt][ks][lane][j] = Wv[ks*32 + (lane>>4)*8 + j][nt*16 + (lane&15)]
__global__ __launch_bounds__(256) void convert_wv_k(const float* __restrict__ wv,
                                                    uint4* __restrict__ wvb) {
    int g = blockIdx.x * 256 + threadIdx.x;  // 2048000
    int l = g & 63, ks = (g >> 6) & 15, nt = g >> 10;
    int n = nt * 16 + (l & 15);
    int k0 = ks * 32 + (l >> 4) * 8;
    const float* p = wv + (size_t)k0 * VS + n;
    unsigned short u[8];
#pragma unroll
    for (int j = 0; j < 8; j++) u[j] = tobf(p[(size_t)j * VS]);
    wvb[g] = *(uint4*)u;
}

// ---------------- Phase A: MFMA bf16 row-sum-of-exp ----------------
// 250 blocks x 4 waves; wave: 128 rows x 32 cols (2 ntiles); block loops all 8 m-chunks.
__global__ __launch_bounds__(256) void phaseA_mfma_k(const uint4* __restrict__ tsb,
                                                     const uint4* __restrict__ wvb,
                                                     const float* __restrict__ bv,
                                                     float* __restrict__ denom) {
    __shared__ float redL[4][128];
    int tid = threadIdx.x;
    int wave = tid >> 6, lane = tid & 63;
    int ntbase = blockIdx.x * 8 + wave * 2;
    float bv0 = bv[ntbase * 16 + (lane & 15)];
    float bv1 = bv[(ntbase + 1) * 16 + (lane & 15)];
    int q = lane >> 4;
    for (int mc = 0; mc < 8; ++mc) {
        f32x4 acc[8][2];
#pragma unroll
        for (int i = 0; i < 8; i++)
#pragma unroll
            for (int j = 0; j < 2; j++) acc[i][j] = 0.0f;
#pragma unroll 4
        for (int ks = 0; ks < 16; ++ks) {
            short8 a[8], b[2];
#pragma unroll
            for (int i = 0; i < 8; i++) {
                int mt = mc * 8 + i;
                uint4 t = tsb[(size_t)(mt * 16 + ks) * 64 + lane];
                a[i] = *reinterpret_cast<short8*>(&t);
            }
#pragma unroll
            for (int j = 0; j < 2; j++) {
                uint4 t = wvb[(size_t)((ntbase + j) * 16 + ks) * 64 + lane];
                b[j] = *reinterpret_cast<short8*>(&t);
            }
#pragma unroll
            for (int i = 0; i < 8; i++)
#pragma unroll
                for (int j = 0; j < 2; j++)
                    acc[i][j] = __builtin_amdgcn_mfma_f32_16x16x32_bf16(a[i], b[j], acc[i][j], 0, 0, 0);
        }
#pragma unroll
        for (int i = 0; i < 8; i++) {
#pragma unroll
            for (int r = 0; r < 4; r++) {
                float e = __expf(acc[i][0][r] + bv0) + __expf(acc[i][1][r] + bv1);
                e += __shfl_xor(e, 1);
                e += __shfl_xor(e, 2);
                e += __shfl_xor(e, 4);
                e += __shfl_xor(e, 8);
                if ((lane & 15) == 0) redL[wave][i * 16 + q * 4 + r] = e;
            }
        }
        __syncthreads();
        if (tid < 128) {
            float v = redL[0][tid] + redL[1][tid] + redL[2][tid] + redL[3][tid];
            atomicAdd(&denom[mc * 128 + tid], v);
        }
        __syncthreads();
    }
}

// ---------------- emission assembly ----------------
__global__ __launch_bounds__(512) void emission_k(const float* __restrict__ ts,
                                                  const float* __restrict__ Wv,
                                                  const float* __restrict__ bv,
                                                  const int* __restrict__ sources,
                                                  const float* __restrict__ ns,
                                                  const float* __restrict__ denom,
                                                  const float* __restrict__ nulld,
                                                  float* __restrict__ em) {
    __shared__ float colv[512];
    __shared__ float red[64][9];
    __shared__ float red2[8];
    __shared__ float env_s, bvc_s;
    int b = blockIdx.y, sc = blockIdx.x;
    int tid = threadIdx.x;
    for (int qq = 0; qq < 8; ++qq) {
        int s = sc * 8 + qq;
        int c = sources[b * 64 + s];
        __syncthreads();
        colv[tid] = Wv[(size_t)tid * VS + c];
        if (tid == 0) bvc_s = bv[c];
        __syncthreads();
        int r = tid & 63, ksl = tid >> 6;
        const float* tr = ts + (size_t)(b * 64 + r) * 512 + ksl * 64;
        float p = 0.f;
#pragma unroll
        for (int k4 = 0; k4 < 16; k4++) {
            float4 t4 = *(const float4*)(tr + k4 * 4);
            float4 c4 = *(const float4*)&colv[ksl * 64 + k4 * 4];
            p += t4.x * c4.x + t4.y * c4.y + t4.z * c4.z + t4.w * c4.w;
        }
        red[r][ksl] = p;
        if (tid < 8) {
            float pn = 0.f;
#pragma unroll
            for (int k4 = 0; k4 < 16; k4++) {
                float4 n4 = *(const float4*)(ns + tid * 64 + k4 * 4);
                float4 c4 = *(const float4*)&colv[tid * 64 + k4 * 4];
                pn += n4.x * c4.x + n4.y * c4.y + n4.z * c4.z + n4.w * c4.w;
            }
            red2[tid] = pn;
        }
        __syncthreads();
        if (tid < 64) {
            float dot = red[tid][0] + red[tid][1] + red[tid][2] + red[tid][3] +
                        red[tid][4] + red[tid][5] + red[tid][6] + red[tid][7];
            float ew = expf(dot + bvc_s) / denom[b * 64 + tid];
            em[(size_t)(b * 128 + tid) * 64 + s] = ew;
        } else if (tid == 64) {
            float dn = red2[0] + red2[1] + red2[2] + red2[3] +
                       red2[4] + red2[5] + red2[6] + red2[7];
            env_s = expf(dn + bvc_s) / nulld[0];
        }
        __syncthreads();
        if (tid < 64) em[(size_t)(b * 128 + 64 + tid) * 64 + s] = env_s;
    }
}

// ---------------- transition ----------------
__global__ __launch_bounds__(256) void transition_k(const float* __restrict__ tt,
                                                    const float* __restrict__ Wj,
                                                    const float* __restrict__ bj,
                                                    const float* __restrict__ Wp0,
                                                    const float* __restrict__ bp0,
                                                    float* __restrict__ trans,
                                                    float* __restrict__ tlog) {
    __shared__ float ttl[512];
    __shared__ float jrow[Jn], ljrow[Jn];
    __shared__ float sred[256];
    __shared__ float p0_s, lp0_s;
    int blk = blockIdx.x;
    int b = blk >> 6, i = blk & 63;
    int tid = threadIdx.x;
    {
        const float* trr = tt + (size_t)blk * 512;
        if (tid < 128) *(float4*)&ttl[tid * 4] = *(const float4*)(trr + tid * 4);
    }
    __syncthreads();
    bool isj = tid < Jn;
    bool isp = tid == Jn;
    float l = 0.f;
    if (isj || isp) {
        const float* wb = isj ? (Wj + tid) : Wp0;
        int stride = isj ? Jn : 1;
        float a = isj ? bj[tid] : bp0[0];
        for (int k = 0; k < 512; k++) a += ttl[k] * wb[(size_t)k * stride];
        l = a;
    }
    sred[tid] = isj ? l : -1e30f;
    __syncthreads();
    for (int o = 128; o > 0; o >>= 1) {
        if (tid < o) sred[tid] = fmaxf(sred[tid], sred[tid + o]);
        __syncthreads();
    }
    float m = sred[0];
    __syncthreads();
    float ex = isj ? expf(l - m) : 0.f;
    sred[tid] = ex;
    __syncthreads();
    for (int o = 128; o > 0; o >>= 1) {
        if (tid < o) sred[tid] += sred[tid + o];
        __syncthreads();
    }
    float S = sred[0];
    if (isj) {
        jrow[tid] = ex / S;
        ljrow[tid] = (l - m) - logf(S);
    }
    if (isp) {
        float pv = 1.f / (1.f + expf(-l));
        p0_s = pv;
        lp0_s = logf(pv);
    }
    __syncthreads();
    if (tid < 128) {
        int j = tid;
        float tv, lv;
        if (j < 64) {
            int id = Mn + j - i;
            tv = jrow[id];
            lv = ljrow[id];
        } else {
            bool dg = (j - 64) == i;
            tv = dg ? p0_s : 0.f;
            lv = dg ? lp0_s : 0.f;
        }
        size_t r1 = (size_t)(b * 128 + i) * 128 + j;
        size_t r2 = (size_t)(b * 128 + 64 + i) * 128 + j;
        trans[r1] = tv;
        trans[r2] = tv;
        tlog[r1] = lv;
        tlog[r2] = lv;
    }
}

extern "C" void kernel_launch(void* const* d_in, const int* in_sizes, int n_in,
                              void* d_out, int out_size, void* d_ws, size_t ws_size,
                              hipStream_t stream) {
    const int* sources = (const int*)d_in[0];
    const int* targets = (const int*)d_in[1];
    const int* tnull = (const int*)d_in[2];
    const int* lengths = (const int*)d_in[3];
    const float* emb = (const float*)d_in[4];
    const float* nnW = (const float*)d_in[5];
    const float* nnb = (const float*)d_in[6];
    const float* Wx_fw = (const float*)d_in[7];
    const float* Wh_fw = (const float*)d_in[8];
    const float* b_fw = (const float*)d_in[9];
    const float* Wx_bw = (const float*)d_in[10];
    const float* Wh_bw = (const float*)d_in[11];
    const float* b_bw = (const float*)d_in[12];
    const float* Wproj_e = (const float*)d_in[13];
    const float* Wv = (const float*)d_in[14];
    const float* bv = (const float*)d_in[15];
    const float* Wproj_t = (const float*)d_in[16];
    const float* Wj = (const float*)d_in[17];
    const float* bj = (const float*)d_in[18];
    const float* Wp0 = (const float*)d_in[19];
    const float* bp0 = (const float*)d_in[20];

    float* ws = (float*)d_ws;
    float* out = (float*)d_out;
    float* out_em = out;                     // [16][128][64]
    float* out_tr = out + 131072;            // [16][128][128]
    float* out_tl = out + 131072 + 262144;   // [16][128][128]

    // 1) zero hcat + denom + nulld + barrier counters
    zero_k<<<(ZERO_N / 4 + 255) / 256, 256, 0, stream>>>((float4*)ws, ZERO_N / 4);

    // 2) gx = gather(emb, targets) @ Wx + b (both directions)
    dim3 g1(2048 / 64, 1024 / 64);
    gemm_k<0><<<g1, 256, 0, stream>>>(emb, Wx_fw, b_fw, ws + O_GX, 1024, 2048, 256, targets);
    gemm_k<0><<<g1, 256, 0, stream>>>(emb, Wx_bw, b_bw, ws + O_GX + 2097152, 1024, 2048, 256, targets);

    // 3) null state + denominator
    null_state_k<<<1, 256, 0, stream>>>(emb, tnull, nnW, nnb, ws + O_NS);
    null_denom_k<<<125, 256, 0, stream>>>(ws + O_NS, Wv, bv, ws + O_NULLD);

    // 4) persistent bidirectional LSTM (single launch)
    lstm_persist_k<<<128, 512, 0, stream>>>(Wh_fw, Wh_bw, ws + O_GX, lengths,
                                            ws + O_H, ws + O_HCAT,
                                            (unsigned*)(ws + O_BAR));

    // 5) projections
    gemm_k<0><<<dim3(512 / 64, 16), 256, 0, stream>>>(ws + O_HCAT, Wproj_e, nullptr,
                                                      ws + O_TS, 1024, 512, 1024, nullptr);
    gemm_k<0><<<dim3(256 / 64, 16), 256, 0, stream>>>(ws + O_HCAT, Wproj_t, nullptr,
                                                      ws + O_TTPRE, 1024, 256, 1024, nullptr);
    gemm_k<1><<<dim3(512 / 64, 16), 256, 0, stream>>>(ws + O_TTPRE, nnW, nnb,
                                                      ws + O_TT, 1024, 512, 256, nullptr);

    // 6) bf16 fragment conversions (gx is dead now; WVB overlaps it)
    convert_ts_k<<<256, 256, 0, stream>>>(ws + O_TS, (uint4*)(ws + O_TSB));
    convert_wv_k<<<8000, 256, 0, stream>>>(Wv, (uint4*)(ws + O_WVB));

    // 7) emission softmax denominators via MFMA
    phaseA_mfma_k<<<250, 256, 0, stream>>>((const uint4*)(ws + O_TSB),
                                           (const uint4*)(ws + O_WVB), bv, ws + O_DENOM);

    // 8) emission output
    emission_k<<<dim3(8, 16), 512, 0, stream>>>(ws + O_TS, Wv, bv, sources, ws + O_NS,
                                                ws + O_DENOM, ws + O_NULLD, out_em);

    // 9) transition outputs
    transition_k<<<1024, 256, 0, stream>>>(ws + O_TT, Wj, bj, Wp0, bp0, out_tr, out_tl);
}

// Round 3
// 1184.580 us; speedup vs baseline: 1.7689x; 1.5200x over previous
//
#include <hip/hip_runtime.h>
#include <hip/hip_bf16.h>
#include <math.h>

// Shapes (fixed by the reference)
#define Bn 16
#define Sn 64
#define Tn 64
#define En 256
#define Hn 512
#define VS 32000
#define Jn 201
#define Mn 100

// Workspace layout (float offsets)
#define O_HCAT   0                      // [1024][1024] fp32
#define O_DENOM  1048576                // [1024]
#define O_NULLD  1049600                // [64]
#define O_SLOTS  1049664                // 32 barrier slots x 64 uints (256B apart)
#define O_HBUF   1051712                // [2 pp][2 dir][16 b][512 u] ushort = 16384 floats
#define ZERO_N   1068096
#define O_NS     1068096                // [512]
#define O_TS     1068608                // [1024][512]
#define O_TSB    1592896                // ts bf16 frags: 262144 floats
#define O_TT     1855040                // [1024][512]
#define O_TTPRE  2379328                // [1024][256]
#define O_WVB    2641472                // Wv bf16 frags: 8192000 floats
#define O_GX     2641472                // [2][1024][2048] (overlaps WVB; gx dead before conversion)

typedef __attribute__((ext_vector_type(8))) short short8;
typedef __attribute__((ext_vector_type(4))) float f32x4;

__device__ __forceinline__ float sigf(float x) { return 1.0f / (1.0f + expf(-x)); }
__device__ __forceinline__ unsigned short tobf(float x) {
    __hip_bfloat16 h = __float2bfloat16(x);
    return *reinterpret_cast<unsigned short*>(&h);
}

// ---------------- zero workspace ----------------
__global__ void zero_k(float4* __restrict__ p, int n4) {
    int i = blockIdx.x * blockDim.x + threadIdx.x;
    if (i < n4) p[i] = make_float4(0.f, 0.f, 0.f, 0.f);
}

// ---------------- generic tiled GEMM: C = act(A@B + bias) ----------------
template <int ACT>
__global__ __launch_bounds__(256) void gemm_k(const float* __restrict__ A,
                                              const float* __restrict__ B,
                                              const float* __restrict__ bias,
                                              float* __restrict__ C,
                                              int M, int N, int K,
                                              const int* __restrict__ gidx) {
    __shared__ float As[16][68];
    __shared__ float Bs[16][68];
    int tid = threadIdx.x;
    int bm = blockIdx.y * 64, bn = blockIdx.x * 64;
    int tm = tid >> 4, tn = tid & 15;
    int ar = tid >> 2, akq = (tid & 3) * 4;
    int bk = tid >> 4, bn4 = (tid & 15) * 4;
    float acc[4][4] = {};
    for (int k0 = 0; k0 < K; k0 += 16) {
        int grow = bm + ar;
        const float* arow = gidx ? (A + (size_t)gidx[grow] * K) : (A + (size_t)grow * K);
        float4 av = *(const float4*)(arow + k0 + akq);
        As[akq + 0][ar] = av.x; As[akq + 1][ar] = av.y;
        As[akq + 2][ar] = av.z; As[akq + 3][ar] = av.w;
        *(float4*)&Bs[bk][bn4] = *(const float4*)(B + (size_t)(k0 + bk) * N + bn + bn4);
        __syncthreads();
#pragma unroll
        for (int kk = 0; kk < 16; ++kk) {
            float a[4], bb[4];
#pragma unroll
            for (int i = 0; i < 4; i++) a[i] = As[kk][tm * 4 + i];
#pragma unroll
            for (int j = 0; j < 4; j++) bb[j] = Bs[kk][tn * 4 + j];
#pragma unroll
            for (int i = 0; i < 4; i++)
#pragma unroll
                for (int j = 0; j < 4; j++) acc[i][j] += a[i] * bb[j];
        }
        __syncthreads();
    }
#pragma unroll
    for (int i = 0; i < 4; i++) {
        int row = bm + tm * 4 + i;
        float4 o;
        float v[4];
#pragma unroll
        for (int j = 0; j < 4; j++) {
            float x = acc[i][j] + (bias ? bias[bn + tn * 4 + j] : 0.f);
            if (ACT == 1) x = tanhf(x);
            v[j] = x;
        }
        o.x = v[0]; o.y = v[1]; o.z = v[2]; o.w = v[3];
        *(float4*)&C[(size_t)row * N + bn + tn * 4] = o;
    }
}

// ---------------- null state ----------------
__global__ __launch_bounds__(256) void null_state_k(const float* __restrict__ emb,
                                                    const int* __restrict__ tnull,
                                                    const float* __restrict__ nnW,
                                                    const float* __restrict__ nnb,
                                                    float* __restrict__ ns) {
    __shared__ float xn[En];
    int t = threadIdx.x;
    xn[t] = emb[(size_t)tnull[0] * En + t];
    __syncthreads();
    for (int h = t; h < Hn; h += 256) {
        float a = nnb[h];
        for (int e = 0; e < En; e++) a += xn[e] * nnW[(size_t)e * Hn + h];
        ns[h] = tanhf(a);
    }
}

// ---------------- null denom ----------------
__global__ __launch_bounds__(256) void null_denom_k(const float* __restrict__ ns,
                                                    const float* __restrict__ Wv,
                                                    const float* __restrict__ bv,
                                                    float* __restrict__ nd) {
    __shared__ float nsl[Hn];
    __shared__ float red[4];
    int t = threadIdx.x;
    int v = blockIdx.x * 256 + t;
    nsl[t] = ns[t];
    nsl[t + 256] = ns[t + 256];
    __syncthreads();
    float a = bv[v];
    for (int k = 0; k < Hn; k++) a += nsl[k] * Wv[(size_t)k * VS + v];
    float e = expf(a);
    for (int o = 1; o < 64; o <<= 1) e += __shfl_xor(e, o);
    if ((t & 63) == 0) red[t >> 6] = e;
    __syncthreads();
    if (t == 0) atomicAdd(nd, red[0] + red[1] + red[2] + red[3]);
}

// ---------------- persistent bidirectional LSTM, MFMA recurrence ----------------
// 32 blocks x 256 threads (4 waves). blk: dir=blk>>4, units u0=(blk&15)*32; wave w owns
// units [u0+w*8, +8). Wh slice pre-swizzled to B-frags in 128KB LDS (once). h exchanged
// as bf16 [pp][dir][b][u] (A-frag-friendly: lane's frag = one uint4). Barrier: one slot
// per block, 256B apart, release store + 32-lane relaxed spin + single acquire load.
__global__ __launch_bounds__(256, 1) void lstm_persist_k(const float* __restrict__ wh_fw,
                                                         const float* __restrict__ wh_bw,
                                                         const float* __restrict__ gx,
                                                         const int* __restrict__ lengths,
                                                         unsigned short* __restrict__ hbuf,
                                                         float* __restrict__ hcat,
                                                         unsigned* __restrict__ slots) {
    __shared__ uint4 whf[8192];       // [w][t][ks][lane] B-frags, 128 KB
    __shared__ float raw[32][129];    // staging tile, 16.5 KB
    __shared__ int lenS[16];
    int tid = threadIdx.x;
    int blk = blockIdx.x;
    int dir = blk >> 4;
    int u0 = (blk & 15) * 32;
    const float* wh = dir ? wh_bw : wh_fw;
    if (tid < 16) lenS[tid] = lengths[tid];

    // ---- one-time Wh -> bf16 B-fragment staging (coalesced via raw tile) ----
    for (int chunk = 0; chunk < 16; ++chunk) {
#pragma unroll
        for (int it = 0; it < 16; ++it) {
            int li = it * 256 + tid;            // 0..4095
            int kl = li >> 7, c = li & 127;
            int g = c >> 5, ub = c & 31;
            raw[kl][c] = wh[(size_t)(chunk * 32 + kl) * 2048 + g * 512 + u0 + ub];
        }
        __syncthreads();
#pragma unroll
        for (int it = 0; it < 2; ++it) {
            int idx = tid * 2 + it;             // 0..511
            int w = idx >> 7, t = (idx >> 6) & 1, lane = idx & 63;
            int n = lane & 15, uu = n >> 1, p = n & 1;
            int cc = (t * 2 + p) * 32 + w * 8 + uu;
            int kb = (lane >> 4) * 8;
            unsigned short u8[8];
#pragma unroll
            for (int j = 0; j < 8; j++) u8[j] = tobf(raw[kb + j][cc]);
            whf[((w * 2 + t) * 16 + chunk) * 64 + lane] = *(uint4*)u8;
        }
        __syncthreads();
    }

    int wv = tid >> 6, lane = tid & 63;
    int n = lane & 15, p = n & 1, uu = n >> 1, q = lane >> 4;
    int u = u0 + wv * 8 + uu;                   // unit this lane-pair owns
    float creg[4] = {0.f, 0.f, 0.f, 0.f};       // c-state for b = q*4+r

    for (int s = 0; s < 64; ++s) {
        // ---- A-frags: h (bf16) for b=lane&15, k-slices ----
        const unsigned short* hb =
            hbuf + (((s & 1) * 2 + dir) * 16 + n) * 512 + q * 8;
        uint4 haf[16];
#pragma unroll
        for (int ks = 0; ks < 16; ks++) haf[ks] = *(const uint4*)(hb + ks * 32);
        f32x4 acc0 = {0.f, 0.f, 0.f, 0.f}, acc1 = {0.f, 0.f, 0.f, 0.f};
#pragma unroll
        for (int ks = 0; ks < 16; ks++) {
            short8 a = *reinterpret_cast<short8*>(&haf[ks]);
            uint4 b0 = whf[((wv * 2 + 0) * 16 + ks) * 64 + lane];
            uint4 b1 = whf[((wv * 2 + 1) * 16 + ks) * 64 + lane];
            acc0 = __builtin_amdgcn_mfma_f32_16x16x32_bf16(a, *reinterpret_cast<short8*>(&b0), acc0, 0, 0, 0);
            acc1 = __builtin_amdgcn_mfma_f32_16x16x32_bf16(a, *reinterpret_cast<short8*>(&b1), acc1, 0, 0, 0);
        }
        // even lane (p=0) has gates i (acc0), f (acc1); odd has j, o of same unit.
        float jv[4], ov[4];
#pragma unroll
        for (int r = 0; r < 4; r++) {
            jv[r] = __shfl_xor(acc0[r], 1);
            ov[r] = __shfl_xor(acc1[r], 1);
        }
        if (p == 0) {
#pragma unroll
            for (int r = 0; r < 4; r++) {
                int b = q * 4 + r;
                int len = lenS[b];
                unsigned short* hwp =
                    hbuf + ((((s + 1) & 1) * 2 + dir) * 16 + b) * 512 + u;
                if (s < len) {
                    int tin = dir ? (len - 1 - s) : s;
                    const float* gxr = gx + (size_t)dir * 2097152 +
                                       (size_t)(b * 64 + tin) * 2048 + u;
                    float gi = acc0[r] + gxr[0];
                    float gj = jv[r] + gxr[512];
                    float gf = acc1[r] + gxr[1024];
                    float go = ov[r] + gxr[1536];
                    float cn = sigf(gf + 1.0f) * creg[r] + sigf(gi) * tanhf(gj);
                    float hn = sigf(go) * tanhf(cn);
                    creg[r] = cn;
                    *hwp = tobf(hn);
                    __builtin_nontemporal_store(
                        hn, &hcat[(size_t)(b * 64 + tin) * 1024 + dir * 512 + u]);
                } else {
                    *hwp = hbuf[(((s & 1) * 2 + dir) * 16 + b) * 512 + u];
                }
            }
        }
        if (s == 63) break;
        __syncthreads();  // all waves' stores drained (vmcnt(0) before s_barrier)
        if (tid == 0)
            __hip_atomic_store(&slots[blk * 64], (unsigned)(s + 1), __ATOMIC_RELEASE,
                               __HIP_MEMORY_SCOPE_AGENT);
        if (tid < 32) {
            while (__hip_atomic_load(&slots[tid * 64], __ATOMIC_RELAXED,
                                     __HIP_MEMORY_SCOPE_AGENT) < (unsigned)(s + 1)) {
                __builtin_amdgcn_s_sleep(2);
            }
        }
        __syncthreads();
        if (tid == 0)  // one acquire (buffer_inv) for the whole CU
            (void)__hip_atomic_load(&slots[0], __ATOMIC_ACQUIRE, __HIP_MEMORY_SCOPE_AGENT);
        __syncthreads();
    }
}

// ---------------- bf16 fragment-swizzle conversions ----------------
__global__ __launch_bounds__(256) void convert_ts_k(const float* __restrict__ ts,
                                                    uint4* __restrict__ tsb) {
    int g = blockIdx.x * 256 + threadIdx.x;  // 65536
    int l = g & 63, ks = (g >> 6) & 15, mt = g >> 10;
    int m = mt * 16 + (l & 15);
    int k0 = ks * 32 + (l >> 4) * 8;
    const float* p = ts + (size_t)m * 512 + k0;
    float4 f0 = *(const float4*)(p);
    float4 f1 = *(const float4*)(p + 4);
    unsigned short u[8] = {tobf(f0.x), tobf(f0.y), tobf(f0.z), tobf(f0.w),
                           tobf(f1.x), tobf(f1.y), tobf(f1.z), tobf(f1.w)};
    tsb[g] = *(uint4*)u;
}

__global__ __launch_bounds__(256) void convert_wv_k(const float* __restrict__ wv,
                                                    uint4* __restrict__ wvb) {
    int g = blockIdx.x * 256 + threadIdx.x;  // 2048000
    int l = g & 63, ks = (g >> 6) & 15, nt = g >> 10;
    int n = nt * 16 + (l & 15);
    int k0 = ks * 32 + (l >> 4) * 8;
    const float* p = wv + (size_t)k0 * VS + n;
    unsigned short u[8];
#pragma unroll
    for (int j = 0; j < 8; j++) u[j] = tobf(p[(size_t)j * VS]);
    wvb[g] = *(uint4*)u;
}

// ---------------- Phase A: MFMA bf16 row-sum-of-exp ----------------
__global__ __launch_bounds__(256) void phaseA_mfma_k(const uint4* __restrict__ tsb,
                                                     const uint4* __restrict__ wvb,
                                                     const float* __restrict__ bv,
                                                     float* __restrict__ denom) {
    __shared__ float redL[4][128];
    int tid = threadIdx.x;
    int wave = tid >> 6, lane = tid & 63;
    int ntbase = blockIdx.x * 8 + wave * 2;
    float bv0 = bv[ntbase * 16 + (lane & 15)];
    float bv1 = bv[(ntbase + 1) * 16 + (lane & 15)];
    int q = lane >> 4;
    for (int mc = 0; mc < 8; ++mc) {
        f32x4 acc[8][2];
#pragma unroll
        for (int i = 0; i < 8; i++)
#pragma unroll
            for (int j = 0; j < 2; j++) acc[i][j] = 0.0f;
#pragma unroll 4
        for (int ks = 0; ks < 16; ++ks) {
            short8 a[8], b[2];
#pragma unroll
            for (int i = 0; i < 8; i++) {
                int mt = mc * 8 + i;
                uint4 t = tsb[(size_t)(mt * 16 + ks) * 64 + lane];
                a[i] = *reinterpret_cast<short8*>(&t);
            }
#pragma unroll
            for (int j = 0; j < 2; j++) {
                uint4 t = wvb[(size_t)((ntbase + j) * 16 + ks) * 64 + lane];
                b[j] = *reinterpret_cast<short8*>(&t);
            }
#pragma unroll
            for (int i = 0; i < 8; i++)
#pragma unroll
                for (int j = 0; j < 2; j++)
                    acc[i][j] = __builtin_amdgcn_mfma_f32_16x16x32_bf16(a[i], b[j], acc[i][j], 0, 0, 0);
        }
#pragma unroll
        for (int i = 0; i < 8; i++) {
#pragma unroll
            for (int r = 0; r < 4; r++) {
                float e = __expf(acc[i][0][r] + bv0) + __expf(acc[i][1][r] + bv1);
                e += __shfl_xor(e, 1);
                e += __shfl_xor(e, 2);
                e += __shfl_xor(e, 4);
                e += __shfl_xor(e, 8);
                if ((lane & 15) == 0) redL[wave][i * 16 + q * 4 + r] = e;
            }
        }
        __syncthreads();
        if (tid < 128) {
            float v = redL[0][tid] + redL[1][tid] + redL[2][tid] + redL[3][tid];
            atomicAdd(&denom[mc * 128 + tid], v);
        }
        __syncthreads();
    }
}

// ---------------- emission assembly ----------------
__global__ __launch_bounds__(512) void emission_k(const float* __restrict__ ts,
                                                  const float* __restrict__ Wv,
                                                  const float* __restrict__ bv,
                                                  const int* __restrict__ sources,
                                                  const float* __restrict__ ns,
                                                  const float* __restrict__ denom,
                                                  const float* __restrict__ nulld,
                                                  float* __restrict__ em) {
    __shared__ float colv[512];
    __shared__ float red[64][9];
    __shared__ float red2[8];
    __shared__ float env_s, bvc_s;
    int b = blockIdx.y, sc = blockIdx.x;
    int tid = threadIdx.x;
    for (int qq = 0; qq < 8; ++qq) {
        int s = sc * 8 + qq;
        int c = sources[b * 64 + s];
        __syncthreads();
        colv[tid] = Wv[(size_t)tid * VS + c];
        if (tid == 0) bvc_s = bv[c];
        __syncthreads();
        int r = tid & 63, ksl = tid >> 6;
        const float* tr = ts + (size_t)(b * 64 + r) * 512 + ksl * 64;
        float p = 0.f;
#pragma unroll
        for (int k4 = 0; k4 < 16; k4++) {
            float4 t4 = *(const float4*)(tr + k4 * 4);
            float4 c4 = *(const float4*)&colv[ksl * 64 + k4 * 4];
            p += t4.x * c4.x + t4.y * c4.y + t4.z * c4.z + t4.w * c4.w;
        }
        red[r][ksl] = p;
        if (tid < 8) {
            float pn = 0.f;
#pragma unroll
            for (int k4 = 0; k4 < 16; k4++) {
                float4 n4 = *(const float4*)(ns + tid * 64 + k4 * 4);
                float4 c4 = *(const float4*)&colv[tid * 64 + k4 * 4];
                pn += n4.x * c4.x + n4.y * c4.y + n4.z * c4.z + n4.w * c4.w;
            }
            red2[tid] = pn;
        }
        __syncthreads();
        if (tid < 64) {
            float dot = red[tid][0] + red[tid][1] + red[tid][2] + red[tid][3] +
                        red[tid][4] + red[tid][5] + red[tid][6] + red[tid][7];
            float ew = expf(dot + bvc_s) / denom[b * 64 + tid];
            em[(size_t)(b * 128 + tid) * 64 + s] = ew;
        } else if (tid == 64) {
            float dn = red2[0] + red2[1] + red2[2] + red2[3] +
                       red2[4] + red2[5] + red2[6] + red2[7];
            env_s = expf(dn + bvc_s) / nulld[0];
        }
        __syncthreads();
        if (tid < 64) em[(size_t)(b * 128 + 64 + tid) * 64 + s] = env_s;
    }
}

// ---------------- transition ----------------
__global__ __launch_bounds__(256) void transition_k(const float* __restrict__ tt,
                                                    const float* __restrict__ Wj,
                                                    const float* __restrict__ bj,
                                                    const float* __restrict__ Wp0,
                                                    const float* __restrict__ bp0,
                                                    float* __restrict__ trans,
                                                    float* __restrict__ tlog) {
    __shared__ float ttl[512];
    __shared__ float jrow[Jn], ljrow[Jn];
    __shared__ float sred[256];
    __shared__ float p0_s, lp0_s;
    int blk = blockIdx.x;
    int b = blk >> 6, i = blk & 63;
    int tid = threadIdx.x;
    {
        const float* trr = tt + (size_t)blk * 512;
        if (tid < 128) *(float4*)&ttl[tid * 4] = *(const float4*)(trr + tid * 4);
    }
    __syncthreads();
    bool isj = tid < Jn;
    bool isp = tid == Jn;
    float l = 0.f;
    if (isj || isp) {
        const float* wb = isj ? (Wj + tid) : Wp0;
        int stride = isj ? Jn : 1;
        float a = isj ? bj[tid] : bp0[0];
        for (int k = 0; k < 512; k++) a += ttl[k] * wb[(size_t)k * stride];
        l = a;
    }
    sred[tid] = isj ? l : -1e30f;
    __syncthreads();
    for (int o = 128; o > 0; o >>= 1) {
        if (tid < o) sred[tid] = fmaxf(sred[tid], sred[tid + o]);
        __syncthreads();
    }
    float m = sred[0];
    __syncthreads();
    float ex = isj ? expf(l - m) : 0.f;
    sred[tid] = ex;
    __syncthreads();
    for (int o = 128; o > 0; o >>= 1) {
        if (tid < o) sred[tid] += sred[tid + o];
        __syncthreads();
    }
    float S = sred[0];
    if (isj) {
        jrow[tid] = ex / S;
        ljrow[tid] = (l - m) - logf(S);
    }
    if (isp) {
        float pv = 1.f / (1.f + expf(-l));
        p0_s = pv;
        lp0_s = logf(pv);
    }
    __syncthreads();
    if (tid < 128) {
        int j = tid;
        float tv, lv;
        if (j < 64) {
            int id = Mn + j - i;
            tv = jrow[id];
            lv = ljrow[id];
        } else {
            bool dg = (j - 64) == i;
            tv = dg ? p0_s : 0.f;
            lv = dg ? lp0_s : 0.f;
        }
        size_t r1 = (size_t)(b * 128 + i) * 128 + j;
        size_t r2 = (size_t)(b * 128 + 64 + i) * 128 + j;
        trans[r1] = tv;
        trans[r2] = tv;
        tlog[r1] = lv;
        tlog[r2] = lv;
    }
}

extern "C" void kernel_launch(void* const* d_in, const int* in_sizes, int n_in,
                              void* d_out, int out_size, void* d_ws, size_t ws_size,
                              hipStream_t stream) {
    const int* sources = (const int*)d_in[0];
    const int* targets = (const int*)d_in[1];
    const int* tnull = (const int*)d_in[2];
    const int* lengths = (const int*)d_in[3];
    const float* emb = (const float*)d_in[4];
    const float* nnW = (const float*)d_in[5];
    const float* nnb = (const float*)d_in[6];
    const float* Wx_fw = (const float*)d_in[7];
    const float* Wh_fw = (const float*)d_in[8];
    const float* b_fw = (const float*)d_in[9];
    const float* Wx_bw = (const float*)d_in[10];
    const float* Wh_bw = (const float*)d_in[11];
    const float* b_bw = (const float*)d_in[12];
    const float* Wproj_e = (const float*)d_in[13];
    const float* Wv = (const float*)d_in[14];
    const float* bv = (const float*)d_in[15];
    const float* Wproj_t = (const float*)d_in[16];
    const float* Wj = (const float*)d_in[17];
    const float* bj = (const float*)d_in[18];
    const float* Wp0 = (const float*)d_in[19];
    const float* bp0 = (const float*)d_in[20];

    float* ws = (float*)d_ws;
    float* out = (float*)d_out;
    float* out_em = out;                     // [16][128][64]
    float* out_tr = out + 131072;            // [16][128][128]
    float* out_tl = out + 131072 + 262144;   // [16][128][128]

    // 1) zero hcat + denom + nulld + barrier slots + hbuf
    zero_k<<<(ZERO_N / 4 + 255) / 256, 256, 0, stream>>>((float4*)ws, ZERO_N / 4);

    // 2) gx = gather(emb, targets) @ Wx + b (both directions)
    dim3 g1(2048 / 64, 1024 / 64);
    gemm_k<0><<<g1, 256, 0, stream>>>(emb, Wx_fw, b_fw, ws + O_GX, 1024, 2048, 256, targets);
    gemm_k<0><<<g1, 256, 0, stream>>>(emb, Wx_bw, b_bw, ws + O_GX + 2097152, 1024, 2048, 256, targets);

    // 3) null state + denominator
    null_state_k<<<1, 256, 0, stream>>>(emb, tnull, nnW, nnb, ws + O_NS);
    null_denom_k<<<125, 256, 0, stream>>>(ws + O_NS, Wv, bv, ws + O_NULLD);

    // 4) persistent bidirectional LSTM (single launch, 32 blocks, MFMA recurrence)
    lstm_persist_k<<<32, 256, 0, stream>>>(Wh_fw, Wh_bw, ws + O_GX, lengths,
                                           (unsigned short*)(ws + O_HBUF), ws + O_HCAT,
                                           (unsigned*)(ws + O_SLOTS));

    // 5) projections
    gemm_k<0><<<dim3(512 / 64, 16), 256, 0, stream>>>(ws + O_HCAT, Wproj_e, nullptr,
                                                      ws + O_TS, 1024, 512, 1024, nullptr);
    gemm_k<0><<<dim3(256 / 64, 16), 256, 0, stream>>>(ws + O_HCAT, Wproj_t, nullptr,
                                                      ws + O_TTPRE, 1024, 256, 1024, nullptr);
    gemm_k<1><<<dim3(512 / 64, 16), 256, 0, stream>>>(ws + O_TTPRE, nnW, nnb,
                                                      ws + O_TT, 1024, 512, 256, nullptr);

    // 6) bf16 fragment conversions (gx dead now; WVB overlaps it)
    convert_ts_k<<<256, 256, 0, stream>>>(ws + O_TS, (uint4*)(ws + O_TSB));
    convert_wv_k<<<8000, 256, 0, stream>>>(Wv, (uint4*)(ws + O_WVB));

    // 7) emission softmax denominators via MFMA
    phaseA_mfma_k<<<250, 256, 0, stream>>>((const uint4*)(ws + O_TSB),
                                           (const uint4*)(ws + O_WVB), bv, ws + O_DENOM);

    // 8) emission output
    emission_k<<<dim3(8, 16), 512, 0, stream>>>(ws + O_TS, Wv, bv, sources, ws + O_NS,
                                                ws + O_DENOM, ws + O_NULLD, out_em);

    // 9) transition outputs
    transition_k<<<1024, 256, 0, stream>>>(ws + O_TT, Wj, bj, Wp0, bp0, out_tr, out_tl);
}

// Round 4
// 1029.004 us; speedup vs baseline: 2.0363x; 1.1512x over previous
//
#include <hip/hip_runtime.h>
#include <hip/hip_bf16.h>
#include <math.h>

// Shapes (fixed by the reference)
#define Bn 16
#define Sn 64
#define Tn 64
#define En 256
#define Hn 512
#define VS 32000
#define Jn 201
#define Mn 100

// Workspace layout (float offsets)
#define O_HCATF  0                      // hcat bf16 A-frags [64 mt][32 ks][64 lane][8] = 524288 fl
#define O_DENOM  524288                 // [1024]
#define O_NULLD  525312                 // [64]
#define O_SLOTS  525376                 // 32 slots x 64 uints (256B apart)
#define O_HBUF   527424                 // u32 [2 pp][2 dir][16 b][256] = 32768 fl
#define ZERO_N   560192
#define O_NS     560192                 // [512]
#define O_TS     560704                 // [1024][512] fp32 -> end 1084992
#define O_TSF    1084992                // ts A-frags bf16 -> 262144 fl -> 1347136
#define O_TTPRE  1347136                // [1024][256] fp32 -> 1609280
#define O_TTPF   1609280                // ttpre A-frags -> 131072 -> 1740352
#define O_TT     1740352                // [1024][512] fp32 -> 2264640
#define O_XF     2264640                // emb-gather A-frags -> 131072 -> 2395712
#define O_WXFW   2395712                // Wx_fw B-frags -> 262144 -> 2657856
#define O_WXBW   2657856                // Wx_bw B-frags -> 262144 -> 2920000
#define O_WPEF   2920000                // Wproj_e B-frags -> 262144 -> 3182144
#define O_WPTF   3182144                // Wproj_t B-frags -> 131072 -> 3313216
#define O_NNWF   3313216                // nnW B-frags -> 65536 -> 3378752
#define O_GX     3378752                // [2][1024][2048] fp32 -> 7573056
#define O_WVB    2264640                // Wv B-frags (overlays XF..GX, dead after LSTM) -> 10456640

typedef __attribute__((ext_vector_type(8))) short short8;
typedef __attribute__((ext_vector_type(4))) float f32x4;

__device__ __forceinline__ float sigf(float x) { return 1.0f / (1.0f + expf(-x)); }
__device__ __forceinline__ unsigned short tobf(float x) {
    __hip_bfloat16 h = __float2bfloat16(x);
    return *reinterpret_cast<unsigned short*>(&h);
}

// ---------------- zero workspace ----------------
__global__ void zero_k(float4* __restrict__ p, int n4) {
    int i = blockIdx.x * blockDim.x + threadIdx.x;
    if (i < n4) p[i] = make_float4(0.f, 0.f, 0.f, 0.f);
}

// ---------------- fp32 [M][K] (opt. row-gather) -> bf16 A-frags ----------------
// out[(mt*Kd+ks)*64+lane] : m = mt*16+(lane&15), k = ks*32+(lane>>4)*8+j
__global__ __launch_bounds__(256) void convA_k(const float* __restrict__ A,
                                               uint4* __restrict__ out, int K,
                                               const int* __restrict__ gidx) {
    int g = blockIdx.x * 256 + threadIdx.x;
    int Kd = K >> 5;
    int lane = g & 63, t = g >> 6;
    int ks = t % Kd, mt = t / Kd;
    int m = mt * 16 + (lane & 15);
    int k0 = ks * 32 + (lane >> 4) * 8;
    const float* p = (gidx ? A + (size_t)gidx[m] * K : A + (size_t)m * K) + k0;
    float4 f0 = *(const float4*)(p);
    float4 f1 = *(const float4*)(p + 4);
    unsigned short u[8] = {tobf(f0.x), tobf(f0.y), tobf(f0.z), tobf(f0.w),
                           tobf(f1.x), tobf(f1.y), tobf(f1.z), tobf(f1.w)};
    out[g] = *(uint4*)u;
}

// ---------------- fp32 [K][N] -> bf16 B-frags ----------------
// out[(nt*Kd+ks)*64+lane] : n = nt*16+(lane&15), k = ks*32+(lane>>4)*8+j
__global__ __launch_bounds__(256) void convB_k(const float* __restrict__ B,
                                               uint4* __restrict__ out, int N, int K) {
    int g = blockIdx.x * 256 + threadIdx.x;
    int Kd = K >> 5;
    int lane = g & 63, t = g >> 6;
    int ks = t % Kd, nt = t / Kd;
    int n = nt * 16 + (lane & 15);
    int k0 = ks * 32 + (lane >> 4) * 8;
    const float* p = B + (size_t)k0 * N + n;
    unsigned short u[8];
#pragma unroll
    for (int j = 0; j < 8; j++) u[j] = tobf(p[(size_t)j * N]);
    out[g] = *(uint4*)u;
}

// ---------------- generic MFMA GEMM: C = act(A@B + bias), fp32 out ----------------
// grid (N/128, M/128), 256 thr; wave w: ntiles bx*8+w*2{,+1}; mtiles by*8..+7.
template <int ACT>
__global__ __launch_bounds__(256) void gemm_mfma_k(const uint4* __restrict__ af,
                                                   const uint4* __restrict__ bf,
                                                   const float* __restrict__ bias,
                                                   float* __restrict__ C, int N, int Kd) {
    int tid = threadIdx.x, w = tid >> 6, lane = tid & 63;
    int ntb = blockIdx.x * 8 + w * 2;
    int mtb = blockIdx.y * 8;
    f32x4 acc[8][2];
#pragma unroll
    for (int i = 0; i < 8; i++)
#pragma unroll
        for (int j = 0; j < 2; j++) acc[i][j] = 0.0f;
    for (int ks = 0; ks < Kd; ++ks) {
        uint4 b0 = bf[(size_t)(ntb * Kd + ks) * 64 + lane];
        uint4 b1 = bf[(size_t)((ntb + 1) * Kd + ks) * 64 + lane];
#pragma unroll
        for (int i = 0; i < 8; i++) {
            uint4 a = af[(size_t)((mtb + i) * Kd + ks) * 64 + lane];
            acc[i][0] = __builtin_amdgcn_mfma_f32_16x16x32_bf16(
                *reinterpret_cast<short8*>(&a), *reinterpret_cast<short8*>(&b0), acc[i][0], 0, 0, 0);
            acc[i][1] = __builtin_amdgcn_mfma_f32_16x16x32_bf16(
                *reinterpret_cast<short8*>(&a), *reinterpret_cast<short8*>(&b1), acc[i][1], 0, 0, 0);
        }
    }
    int n0 = ntb * 16 + (lane & 15);
    int q = lane >> 4;
    float bs0 = bias ? bias[n0] : 0.f;
    float bs1 = bias ? bias[n0 + 16] : 0.f;
#pragma unroll
    for (int i = 0; i < 8; i++)
#pragma unroll
        for (int r = 0; r < 4; r++) {
            int m = (mtb + i) * 16 + q * 4 + r;
            float v0 = acc[i][0][r] + bs0;
            float v1 = acc[i][1][r] + bs1;
            if (ACT == 1) { v0 = tanhf(v0); v1 = tanhf(v1); }
            C[(size_t)m * N + n0] = v0;
            C[(size_t)m * N + n0 + 16] = v1;
        }
}

// ---------------- null state ----------------
__global__ __launch_bounds__(256) void null_state_k(const float* __restrict__ emb,
                                                    const int* __restrict__ tnull,
                                                    const float* __restrict__ nnW,
                                                    const float* __restrict__ nnb,
                                                    float* __restrict__ ns) {
    __shared__ float xn[En];
    int t = threadIdx.x;
    xn[t] = emb[(size_t)tnull[0] * En + t];
    __syncthreads();
    for (int h = t; h < Hn; h += 256) {
        float a = nnb[h];
        for (int e = 0; e < En; e++) a += xn[e] * nnW[(size_t)e * Hn + h];
        ns[h] = tanhf(a);
    }
}

// ---------------- null denom ----------------
__global__ __launch_bounds__(256) void null_denom_k(const float* __restrict__ ns,
                                                    const float* __restrict__ Wv,
                                                    const float* __restrict__ bv,
                                                    float* __restrict__ nd) {
    __shared__ float nsl[Hn];
    __shared__ float red[4];
    int t = threadIdx.x;
    int v = blockIdx.x * 256 + t;
    nsl[t] = ns[t];
    nsl[t + 256] = ns[t + 256];
    __syncthreads();
    float a = bv[v];
    for (int k = 0; k < Hn; k++) a += nsl[k] * Wv[(size_t)k * VS + v];
    float e = expf(a);
    for (int o = 1; o < 64; o <<= 1) e += __shfl_xor(e, o);
    if ((t & 63) == 0) red[t >> 6] = e;
    __syncthreads();
    if (t == 0) atomicAdd(nd, red[0] + red[1] + red[2] + red[3]);
}

// ---------------- persistent bidirectional LSTM, MFMA + bypass-atomic exchange ----------------
// 32 blocks x 256 threads. dir=blk>>4, u0=(blk&15)*32. Wh B-frags in LDS (staged once).
// h ping-pong as packed-u32 bf16 pairs, moved ONLY via relaxed agent atomics (sc0 sc1 -> IF,
// no L2 maintenance). Per-dir 16-block barrier: release flag store + relaxed polls, NO acquire.
__global__ __launch_bounds__(256, 1) void lstm_persist_k(const float* __restrict__ wh_fw,
                                                         const float* __restrict__ wh_bw,
                                                         const float* __restrict__ gx,
                                                         const int* __restrict__ lengths,
                                                         unsigned* __restrict__ hbuf32,
                                                         unsigned* __restrict__ hcat32,
                                                         unsigned* __restrict__ slots) {
    __shared__ uint4 whf[8192];       // 128 KB B-frags
    __shared__ float raw[32][129];
    __shared__ int lenS[16];
    int tid = threadIdx.x;
    int blk = blockIdx.x;
    int dir = blk >> 4;
    int u0 = (blk & 15) * 32;
    const float* wh = dir ? wh_bw : wh_fw;
    if (tid < 16) lenS[tid] = lengths[tid];

    // one-time Wh -> bf16 B-frag staging
    for (int chunk = 0; chunk < 16; ++chunk) {
#pragma unroll
        for (int it = 0; it < 16; ++it) {
            int li = it * 256 + tid;
            int kl = li >> 7, c = li & 127;
            int g = c >> 5, ub = c & 31;
            raw[kl][c] = wh[(size_t)(chunk * 32 + kl) * 2048 + g * 512 + u0 + ub];
        }
        __syncthreads();
#pragma unroll
        for (int it = 0; it < 2; ++it) {
            int idx = tid * 2 + it;
            int w = idx >> 7, t = (idx >> 6) & 1, lane = idx & 63;
            int n = lane & 15, uu = n >> 1, p = n & 1;
            int cc = (t * 2 + p) * 32 + w * 8 + uu;
            int kb = (lane >> 4) * 8;
            unsigned short u8[8];
#pragma unroll
            for (int j = 0; j < 8; j++) u8[j] = tobf(raw[kb + j][cc]);
            whf[((w * 2 + t) * 16 + chunk) * 64 + lane] = *(uint4*)u8;
        }
        __syncthreads();
    }

    int wv = tid >> 6, lane = tid & 63;
    int n = lane & 15, uu = n >> 1, q = lane >> 4;
    int u = u0 + wv * 8 + uu;
    float creg[4] = {0.f, 0.f, 0.f, 0.f};
    unsigned short hbf[4] = {0, 0, 0, 0};

    for (int s = 0; s < 64; ++s) {
        // ---- A-frags: bypass-atomic u64 loads of h (b = n, k = units) ----
        const unsigned long long* hb64 =
            (const unsigned long long*)(hbuf32 + (((s & 1) * 2 + dir) * 16) * 256);
        unsigned long long h64[32];
#pragma unroll
        for (int ks = 0; ks < 16; ks++) {
            int idx = n * 128 + ks * 8 + q * 2;
            h64[2 * ks] = __hip_atomic_load(hb64 + idx, __ATOMIC_RELAXED, __HIP_MEMORY_SCOPE_AGENT);
            h64[2 * ks + 1] = __hip_atomic_load(hb64 + idx + 1, __ATOMIC_RELAXED, __HIP_MEMORY_SCOPE_AGENT);
        }
        // ---- gx prefetch (independent of exchange) ----
        float gxi[4], gxj[4], gxf[4], gxo[4];
#pragma unroll
        for (int r = 0; r < 4; r++) {
            int b = q * 4 + r;
            int len = lenS[b];
            int tc = dir ? (len - 1 - s) : s;
            tc = tc < 0 ? 0 : tc;
            const float* gp = gx + (size_t)dir * 2097152 + (size_t)(b * 64 + tc) * 2048 + u;
            gxi[r] = gp[0]; gxj[r] = gp[512]; gxf[r] = gp[1024]; gxo[r] = gp[1536];
        }
        // ---- MFMA ----
        f32x4 acc0 = {0.f, 0.f, 0.f, 0.f}, acc1 = {0.f, 0.f, 0.f, 0.f};
#pragma unroll
        for (int ks = 0; ks < 16; ks++) {
            unsigned long long av[2] = {h64[2 * ks], h64[2 * ks + 1]};
            short8 a = *reinterpret_cast<short8*>(av);
            uint4 b0 = whf[((wv * 2 + 0) * 16 + ks) * 64 + lane];
            uint4 b1 = whf[((wv * 2 + 1) * 16 + ks) * 64 + lane];
            acc0 = __builtin_amdgcn_mfma_f32_16x16x32_bf16(a, *reinterpret_cast<short8*>(&b0), acc0, 0, 0, 0);
            acc1 = __builtin_amdgcn_mfma_f32_16x16x32_bf16(a, *reinterpret_cast<short8*>(&b1), acc1, 0, 0, 0);
        }
        // ---- gates (even lanes i/f in acc0/acc1; odd lanes j/o) ----
#pragma unroll
        for (int r = 0; r < 4; r++) {
            float jvv = __shfl_xor(acc0[r], 1);
            float ovv = __shfl_xor(acc1[r], 1);
            int b = q * 4 + r;
            int len = lenS[b];
            float gi = acc0[r] + gxi[r];
            float gj = jvv + gxj[r];
            float gf = acc1[r] + gxf[r];
            float go = ovv + gxo[r];
            float cn = sigf(gf + 1.0f) * creg[r] + sigf(gi) * tanhf(gj);
            float hn = sigf(go) * tanhf(cn);
            if (s < len) { creg[r] = cn; hbf[r] = tobf(hn); }
        }
        // ---- pack unit pairs and store (lanes n%4==0 own units u,u+1) ----
#pragma unroll
        for (int r = 0; r < 4; r++) {
            unsigned self = hbf[r];
            unsigned part = (unsigned)__shfl_xor((int)self, 2) & 0xffffu;
            if ((n & 3) == 0) {
                unsigned pk = self | (part << 16);
                int b = q * 4 + r;
                __hip_atomic_store(
                    hbuf32 + ((((s + 1) & 1) * 2 + dir) * 16 + b) * 256 + (u >> 1), pk,
                    __ATOMIC_RELAXED, __HIP_MEMORY_SCOPE_AGENT);
                int len = lenS[b];
                if (s < len) {
                    int tin = dir ? (len - 1 - s) : s;
                    int row = b * 64 + tin, col = dir * 512 + u;
                    int mt = row >> 4, ksx = col >> 5;
                    int lanep = (row & 15) | (((col >> 3) & 3) << 4);
                    hcat32[(size_t)(((mt * 32 + ksx) * 64 + lanep) * 4) + ((col & 7) >> 1)] = pk;
                }
            }
        }
        if (s == 63) break;
        __syncthreads();  // per-wave vmcnt(0) drain before barrier
        if (tid == 0)
            __hip_atomic_store(&slots[blk * 64], (unsigned)(s + 1), __ATOMIC_RELEASE,
                               __HIP_MEMORY_SCOPE_AGENT);
        if (tid < 16) {
            while (__hip_atomic_load(&slots[(dir * 16 + tid) * 64], __ATOMIC_RELAXED,
                                     __HIP_MEMORY_SCOPE_AGENT) < (unsigned)(s + 1)) {
                __builtin_amdgcn_s_sleep(1);
            }
        }
        __syncthreads();
    }
}

// ---------------- Phase A: MFMA bf16 row-sum-of-exp ----------------
__global__ __launch_bounds__(256) void phaseA_mfma_k(const uint4* __restrict__ tsb,
                                                     const uint4* __restrict__ wvb,
                                                     const float* __restrict__ bv,
                                                     float* __restrict__ denom) {
    __shared__ float redL[4][128];
    int tid = threadIdx.x;
    int wave = tid >> 6, lane = tid & 63;
    int ntbase = blockIdx.x * 8 + wave * 2;
    float bv0 = bv[ntbase * 16 + (lane & 15)];
    float bv1 = bv[(ntbase + 1) * 16 + (lane & 15)];
    int q = lane >> 4;
    for (int mc = 0; mc < 8; ++mc) {
        f32x4 acc[8][2];
#pragma unroll
        for (int i = 0; i < 8; i++)
#pragma unroll
            for (int j = 0; j < 2; j++) acc[i][j] = 0.0f;
#pragma unroll 4
        for (int ks = 0; ks < 16; ++ks) {
            short8 a[8], b[2];
#pragma unroll
            for (int i = 0; i < 8; i++) {
                int mt = mc * 8 + i;
                uint4 t = tsb[(size_t)(mt * 16 + ks) * 64 + lane];
                a[i] = *reinterpret_cast<short8*>(&t);
            }
#pragma unroll
            for (int j = 0; j < 2; j++) {
                uint4 t = wvb[(size_t)((ntbase + j) * 16 + ks) * 64 + lane];
                b[j] = *reinterpret_cast<short8*>(&t);
            }
#pragma unroll
            for (int i = 0; i < 8; i++)
#pragma unroll
                for (int j = 0; j < 2; j++)
                    acc[i][j] = __builtin_amdgcn_mfma_f32_16x16x32_bf16(a[i], b[j], acc[i][j], 0, 0, 0);
        }
#pragma unroll
        for (int i = 0; i < 8; i++) {
#pragma unroll
            for (int r = 0; r < 4; r++) {
                float e = __expf(acc[i][0][r] + bv0) + __expf(acc[i][1][r] + bv1);
                e += __shfl_xor(e, 1);
                e += __shfl_xor(e, 2);
                e += __shfl_xor(e, 4);
                e += __shfl_xor(e, 8);
                if ((lane & 15) == 0) redL[wave][i * 16 + q * 4 + r] = e;
            }
        }
        __syncthreads();
        if (tid < 128) {
            float v = redL[0][tid] + redL[1][tid] + redL[2][tid] + redL[3][tid];
            atomicAdd(&denom[mc * 128 + tid], v);
        }
        __syncthreads();
    }
}

// ---------------- emission assembly ----------------
__global__ __launch_bounds__(512) void emission_k(const float* __restrict__ ts,
                                                  const float* __restrict__ Wv,
                                                  const float* __restrict__ bv,
                                                  const int* __restrict__ sources,
                                                  const float* __restrict__ ns,
                                                  const float* __restrict__ denom,
                                                  const float* __restrict__ nulld,
                                                  float* __restrict__ em) {
    __shared__ float colv[512];
    __shared__ float red[64][9];
    __shared__ float red2[8];
    __shared__ float env_s, bvc_s;
    int b = blockIdx.y, sc = blockIdx.x;
    int tid = threadIdx.x;
    for (int qq = 0; qq < 8; ++qq) {
        int s = sc * 8 + qq;
        int c = sources[b * 64 + s];
        __syncthreads();
        colv[tid] = Wv[(size_t)tid * VS + c];
        if (tid == 0) bvc_s = bv[c];
        __syncthreads();
        int r = tid & 63, ksl = tid >> 6;
        const float* tr = ts + (size_t)(b * 64 + r) * 512 + ksl * 64;
        float p = 0.f;
#pragma unroll
        for (int k4 = 0; k4 < 16; k4++) {
            float4 t4 = *(const float4*)(tr + k4 * 4);
            float4 c4 = *(const float4*)&colv[ksl * 64 + k4 * 4];
            p += t4.x * c4.x + t4.y * c4.y + t4.z * c4.z + t4.w * c4.w;
        }
        red[r][ksl] = p;
        if (tid < 8) {
            float pn = 0.f;
#pragma unroll
            for (int k4 = 0; k4 < 16; k4++) {
                float4 n4 = *(const float4*)(ns + tid * 64 + k4 * 4);
                float4 c4 = *(const float4*)&colv[tid * 64 + k4 * 4];
                pn += n4.x * c4.x + n4.y * c4.y + n4.z * c4.z + n4.w * c4.w;
            }
            red2[tid] = pn;
        }
        __syncthreads();
        if (tid < 64) {
            float dot = red[tid][0] + red[tid][1] + red[tid][2] + red[tid][3] +
                        red[tid][4] + red[tid][5] + red[tid][6] + red[tid][7];
            float ew = expf(dot + bvc_s) / denom[b * 64 + tid];
            em[(size_t)(b * 128 + tid) * 64 + s] = ew;
        } else if (tid == 64) {
            float dn = red2[0] + red2[1] + red2[2] + red2[3] +
                       red2[4] + red2[5] + red2[6] + red2[7];
            env_s = expf(dn + bvc_s) / nulld[0];
        }
        __syncthreads();
        if (tid < 64) em[(size_t)(b * 128 + 64 + tid) * 64 + s] = env_s;
    }
}

// ---------------- transition ----------------
__global__ __launch_bounds__(256) void transition_k(const float* __restrict__ tt,
                                                    const float* __restrict__ Wj,
                                                    const float* __restrict__ bj,
                                                    const float* __restrict__ Wp0,
                                                    const float* __restrict__ bp0,
                                                    float* __restrict__ trans,
                                                    float* __restrict__ tlog) {
    __shared__ float ttl[512];
    __shared__ float jrow[Jn], ljrow[Jn];
    __shared__ float sred[256];
    __shared__ float p0_s, lp0_s;
    int blk = blockIdx.x;
    int b = blk >> 6, i = blk & 63;
    int tid = threadIdx.x;
    {
        const float* trr = tt + (size_t)blk * 512;
        if (tid < 128) *(float4*)&ttl[tid * 4] = *(const float4*)(trr + tid * 4);
    }
    __syncthreads();
    bool isj = tid < Jn;
    bool isp = tid == Jn;
    float l = 0.f;
    if (isj || isp) {
        const float* wb = isj ? (Wj + tid) : Wp0;
        int stride = isj ? Jn : 1;
        float a = isj ? bj[tid] : bp0[0];
        for (int k = 0; k < 512; k++) a += ttl[k] * wb[(size_t)k * stride];
        l = a;
    }
    sred[tid] = isj ? l : -1e30f;
    __syncthreads();
    for (int o = 128; o > 0; o >>= 1) {
        if (tid < o) sred[tid] = fmaxf(sred[tid], sred[tid + o]);
        __syncthreads();
    }
    float m = sred[0];
    __syncthreads();
    float ex = isj ? expf(l - m) : 0.f;
    sred[tid] = ex;
    __syncthreads();
    for (int o = 128; o > 0; o >>= 1) {
        if (tid < o) sred[tid] += sred[tid + o];
        __syncthreads();
    }
    float S = sred[0];
    if (isj) {
        jrow[tid] = ex / S;
        ljrow[tid] = (l - m) - logf(S);
    }
    if (isp) {
        float pv = 1.f / (1.f + expf(-l));
        p0_s = pv;
        lp0_s = logf(pv);
    }
    __syncthreads();
    if (tid < 128) {
        int j = tid;
        float tv, lv;
        if (j < 64) {
            int id = Mn + j - i;
            tv = jrow[id];
            lv = ljrow[id];
        } else {
            bool dg = (j - 64) == i;
            tv = dg ? p0_s : 0.f;
            lv = dg ? lp0_s : 0.f;
        }
        size_t r1 = (size_t)(b * 128 + i) * 128 + j;
        size_t r2 = (size_t)(b * 128 + 64 + i) * 128 + j;
        trans[r1] = tv;
        trans[r2] = tv;
        tlog[r1] = lv;
        tlog[r2] = lv;
    }
}

extern "C" void kernel_launch(void* const* d_in, const int* in_sizes, int n_in,
                              void* d_out, int out_size, void* d_ws, size_t ws_size,
                              hipStream_t stream) {
    const int* sources = (const int*)d_in[0];
    const int* targets = (const int*)d_in[1];
    const int* tnull = (const int*)d_in[2];
    const int* lengths = (const int*)d_in[3];
    const float* emb = (const float*)d_in[4];
    const float* nnW = (const float*)d_in[5];
    const float* nnb = (const float*)d_in[6];
    const float* Wx_fw = (const float*)d_in[7];
    const float* Wh_fw = (const float*)d_in[8];
    const float* b_fw = (const float*)d_in[9];
    const float* Wx_bw = (const float*)d_in[10];
    const float* Wh_bw = (const float*)d_in[11];
    const float* b_bw = (const float*)d_in[12];
    const float* Wproj_e = (const float*)d_in[13];
    const float* Wv = (const float*)d_in[14];
    const float* bv = (const float*)d_in[15];
    const float* Wproj_t = (const float*)d_in[16];
    const float* Wj = (const float*)d_in[17];
    const float* bj = (const float*)d_in[18];
    const float* Wp0 = (const float*)d_in[19];
    const float* bp0 = (const float*)d_in[20];

    float* ws = (float*)d_ws;
    float* out = (float*)d_out;
    float* out_em = out;                     // [16][128][64]
    float* out_tr = out + 131072;            // [16][128][128]
    float* out_tl = out + 131072 + 262144;   // [16][128][128]

    // 1) zero hcat-frags + denom + nulld + slots + hbuf
    zero_k<<<(ZERO_N / 4 + 255) / 256, 256, 0, stream>>>((float4*)ws, ZERO_N / 4);

    // 2) input-side converts
    convA_k<<<128, 256, 0, stream>>>(emb, (uint4*)(ws + O_XF), 256, targets);
    convB_k<<<256, 256, 0, stream>>>(Wx_fw, (uint4*)(ws + O_WXFW), 2048, 256);
    convB_k<<<256, 256, 0, stream>>>(Wx_bw, (uint4*)(ws + O_WXBW), 2048, 256);
    convB_k<<<256, 256, 0, stream>>>(Wproj_e, (uint4*)(ws + O_WPEF), 512, 1024);
    convB_k<<<128, 256, 0, stream>>>(Wproj_t, (uint4*)(ws + O_WPTF), 256, 1024);
    convB_k<<<64, 256, 0, stream>>>(nnW, (uint4*)(ws + O_NNWF), 512, 256);

    // 3) gx = gather(emb,targets) @ Wx + b  (MFMA)
    gemm_mfma_k<0><<<dim3(16, 8), 256, 0, stream>>>((uint4*)(ws + O_XF), (uint4*)(ws + O_WXFW),
                                                    b_fw, ws + O_GX, 2048, 8);
    gemm_mfma_k<0><<<dim3(16, 8), 256, 0, stream>>>((uint4*)(ws + O_XF), (uint4*)(ws + O_WXBW),
                                                    b_bw, ws + O_GX + 2097152, 2048, 8);

    // 4) null state + denominator
    null_state_k<<<1, 256, 0, stream>>>(emb, tnull, nnW, nnb, ws + O_NS);
    null_denom_k<<<125, 256, 0, stream>>>(ws + O_NS, Wv, bv, ws + O_NULLD);

    // 5) persistent bidirectional LSTM
    lstm_persist_k<<<32, 256, 0, stream>>>(Wh_fw, Wh_bw, ws + O_GX, lengths,
                                           (unsigned*)(ws + O_HBUF), (unsigned*)(ws + O_HCATF),
                                           (unsigned*)(ws + O_SLOTS));

    // 6) projections (MFMA on hcat frags)
    gemm_mfma_k<0><<<dim3(4, 8), 256, 0, stream>>>((uint4*)(ws + O_HCATF), (uint4*)(ws + O_WPEF),
                                                   nullptr, ws + O_TS, 512, 32);
    gemm_mfma_k<0><<<dim3(2, 8), 256, 0, stream>>>((uint4*)(ws + O_HCATF), (uint4*)(ws + O_WPTF),
                                                   nullptr, ws + O_TTPRE, 256, 32);
    convA_k<<<128, 256, 0, stream>>>(ws + O_TTPRE, (uint4*)(ws + O_TTPF), 256, nullptr);
    gemm_mfma_k<1><<<dim3(4, 8), 256, 0, stream>>>((uint4*)(ws + O_TTPF), (uint4*)(ws + O_NNWF),
                                                   nnb, ws + O_TT, 512, 8);
    convA_k<<<256, 256, 0, stream>>>(ws + O_TS, (uint4*)(ws + O_TSF), 512, nullptr);

    // 7) Wv -> B-frags (overlays gx region, dead now), then phase A
    convB_k<<<8000, 256, 0, stream>>>(Wv, (uint4*)(ws + O_WVB), VS, 512);
    phaseA_mfma_k<<<250, 256, 0, stream>>>((const uint4*)(ws + O_TSF),
                                           (const uint4*)(ws + O_WVB), bv, ws + O_DENOM);

    // 8) emission output
    emission_k<<<dim3(8, 16), 512, 0, stream>>>(ws + O_TS, Wv, bv, sources, ws + O_NS,
                                                ws + O_DENOM, ws + O_NULLD, out_em);

    // 9) transition outputs
    transition_k<<<1024, 256, 0, stream>>>(ws + O_TT, Wj, bj, Wp0, bp0, out_tr, out_tl);
}

// Round 6
// 971.168 us; speedup vs baseline: 2.1576x; 1.0596x over previous
//
#include <hip/hip_runtime.h>
#include <hip/hip_bf16.h>
#include <math.h>

// Shapes (fixed by the reference)
#define Bn 16
#define Sn 64
#define Tn 64
#define En 256
#define Hn 512
#define VS 32000
#define Jn 201
#define Mn 100

// Workspace layout (float offsets)
#define O_HCATF  0                      // hcat bf16 A-frags [64 mt][32 ks][64 lane][8] = 524288 fl
#define O_DENOM  524288                 // [1024]
#define O_NULLD  525312                 // [64]
#define O_SLOTS  525376                 // 32 slots x 64 uints (256B apart)
#define O_HBUF   527424                 // u32 [2 pp][2 dir][16 b][256] = 32768 fl
#define ZERO_N   560192
#define O_NS     560192                 // [512]
#define O_TS     560704                 // [1024][512] fp32 -> end 1084992
#define O_TSF    1084992                // ts A-frags bf16 -> 262144 fl -> 1347136
#define O_TTPRE  1347136                // [1024][256] fp32 -> 1609280
#define O_TTPF   1609280                // ttpre A-frags -> 131072 -> 1740352
#define O_TT     1740352                // [1024][512] fp32 -> 2264640
#define O_XF     2264640                // emb-gather A-frags -> 131072 -> 2395712
#define O_WXFW   2395712                // Wx_fw B-frags -> 262144 -> 2657856
#define O_WXBW   2657856                // Wx_bw B-frags -> 262144 -> 2920000
#define O_WPEF   2920000                // Wproj_e B-frags -> 262144 -> 3182144
#define O_WPTF   3182144                // Wproj_t B-frags -> 131072 -> 3313216
#define O_NNWF   3313216                // nnW B-frags -> 65536 -> 3378752
#define O_GX     3378752                // [2][1024][2048] fp32 -> 7573056
#define O_WVB    2264640                // Wv B-frags (overlays XF..GX, dead after LSTM)

typedef __attribute__((ext_vector_type(8))) short short8;
typedef __attribute__((ext_vector_type(4))) float f32x4;

__device__ __forceinline__ float sigf(float x) { return 1.0f / (1.0f + expf(-x)); }
__device__ __forceinline__ unsigned short tobf(float x) {
    __hip_bfloat16 h = __float2bfloat16(x);
    return *reinterpret_cast<unsigned short*>(&h);
}

// ---------------- device conversion bodies ----------------
__device__ __forceinline__ void dconvA(const float* __restrict__ A, uint4* __restrict__ out,
                                       int K, const int* __restrict__ gidx, int g) {
    int Kd = K >> 5;
    int lane = g & 63, t = g >> 6;
    int ks = t % Kd, mt = t / Kd;
    int m = mt * 16 + (lane & 15);
    int k0 = ks * 32 + (lane >> 4) * 8;
    const float* p = (gidx ? A + (size_t)gidx[m] * K : A + (size_t)m * K) + k0;
    float4 f0 = *(const float4*)(p);
    float4 f1 = *(const float4*)(p + 4);
    unsigned short u[8] = {tobf(f0.x), tobf(f0.y), tobf(f0.z), tobf(f0.w),
                           tobf(f1.x), tobf(f1.y), tobf(f1.z), tobf(f1.w)};
    out[g] = *(uint4*)u;
}

__device__ __forceinline__ void dconvB(const float* __restrict__ B, uint4* __restrict__ out,
                                       int N, int K, int g) {
    int Kd = K >> 5;
    int lane = g & 63, t = g >> 6;
    int ks = t % Kd, nt = t / Kd;
    int n = nt * 16 + (lane & 15);
    int k0 = ks * 32 + (lane >> 4) * 8;
    const float* p = B + (size_t)k0 * N + n;
    unsigned short u[8];
#pragma unroll
    for (int j = 0; j < 8; j++) u[j] = tobf(p[(size_t)j * N]);
    out[g] = *(uint4*)u;
}

// ---------------- standalone converts (mid-pipeline uses) ----------------
__global__ __launch_bounds__(256) void convA_k(const float* __restrict__ A,
                                               uint4* __restrict__ out, int K,
                                               const int* __restrict__ gidx) {
    dconvA(A, out, K, gidx, blockIdx.x * 256 + threadIdx.x);
}
__global__ __launch_bounds__(256) void convB_k(const float* __restrict__ B,
                                               uint4* __restrict__ out, int N, int K) {
    dconvB(B, out, N, K, blockIdx.x * 256 + threadIdx.x);
}

// ---------------- fused prolog: zero + all input-side converts ----------------
__global__ __launch_bounds__(256) void mega_prep_k(float4* __restrict__ zdst, int zn4,
                                                   const float* __restrict__ emb,
                                                   const int* __restrict__ targets,
                                                   uint4* __restrict__ xf,
                                                   const float* __restrict__ wxfw, uint4* __restrict__ wxfwf,
                                                   const float* __restrict__ wxbw, uint4* __restrict__ wxbwf,
                                                   const float* __restrict__ wpe, uint4* __restrict__ wpef,
                                                   const float* __restrict__ wpt, uint4* __restrict__ wptf,
                                                   const float* __restrict__ nnw, uint4* __restrict__ nnwf) {
    int blk = blockIdx.x, tid = threadIdx.x;
    if (blk < 548) {
        int i = blk * 256 + tid;
        if (i < zn4) zdst[i] = make_float4(0.f, 0.f, 0.f, 0.f);
    } else if (blk < 676) {
        dconvA(emb, xf, 256, targets, (blk - 548) * 256 + tid);
    } else if (blk < 932) {
        dconvB(wxfw, wxfwf, 2048, 256, (blk - 676) * 256 + tid);
    } else if (blk < 1188) {
        dconvB(wxbw, wxbwf, 2048, 256, (blk - 932) * 256 + tid);
    } else if (blk < 1444) {
        dconvB(wpe, wpef, 512, 1024, (blk - 1188) * 256 + tid);
    } else if (blk < 1572) {
        dconvB(wpt, wptf, 256, 1024, (blk - 1444) * 256 + tid);
    } else {
        dconvB(nnw, nnwf, 512, 256, (blk - 1572) * 256 + tid);
    }
}

// ---------------- generic MFMA GEMM: C = act(A@B + bias), fp32 out ----------------
template <int ACT>
__global__ __launch_bounds__(256) void gemm_mfma_k(const uint4* __restrict__ af,
                                                   const uint4* __restrict__ bf,
                                                   const float* __restrict__ bias,
                                                   float* __restrict__ C, int N, int Kd) {
    int tid = threadIdx.x, w = tid >> 6, lane = tid & 63;
    int ntb = blockIdx.x * 8 + w * 2;
    int mtb = blockIdx.y * 8;
    f32x4 acc[8][2];
#pragma unroll
    for (int i = 0; i < 8; i++)
#pragma unroll
        for (int j = 0; j < 2; j++) acc[i][j] = 0.0f;
    for (int ks = 0; ks < Kd; ++ks) {
        uint4 b0 = bf[(size_t)(ntb * Kd + ks) * 64 + lane];
        uint4 b1 = bf[(size_t)((ntb + 1) * Kd + ks) * 64 + lane];
#pragma unroll
        for (int i = 0; i < 8; i++) {
            uint4 a = af[(size_t)((mtb + i) * Kd + ks) * 64 + lane];
            acc[i][0] = __builtin_amdgcn_mfma_f32_16x16x32_bf16(
                *reinterpret_cast<short8*>(&a), *reinterpret_cast<short8*>(&b0), acc[i][0], 0, 0, 0);
            acc[i][1] = __builtin_amdgcn_mfma_f32_16x16x32_bf16(
                *reinterpret_cast<short8*>(&a), *reinterpret_cast<short8*>(&b1), acc[i][1], 0, 0, 0);
        }
    }
    int n0 = ntb * 16 + (lane & 15);
    int q = lane >> 4;
    float bs0 = bias ? bias[n0] : 0.f;
    float bs1 = bias ? bias[n0 + 16] : 0.f;
#pragma unroll
    for (int i = 0; i < 8; i++)
#pragma unroll
        for (int r = 0; r < 4; r++) {
            int m = (mtb + i) * 16 + q * 4 + r;
            float v0 = acc[i][0][r] + bs0;
            float v1 = acc[i][1][r] + bs1;
            if (ACT == 1) { v0 = tanhf(v0); v1 = tanhf(v1); }
            C[(size_t)m * N + n0] = v0;
            C[(size_t)m * N + n0 + 16] = v1;
        }
}

// ---------------- fused null state + denom ----------------
__global__ __launch_bounds__(256) void null_fused_k(const float* __restrict__ emb,
                                                    const int* __restrict__ tnull,
                                                    const float* __restrict__ nnW,
                                                    const float* __restrict__ nnb,
                                                    const float* __restrict__ Wv,
                                                    const float* __restrict__ bv,
                                                    float* __restrict__ ns,
                                                    float* __restrict__ nd) {
    __shared__ float xn[En];
    __shared__ float nsl[Hn];
    __shared__ float red[4];
    int t = threadIdx.x;
    xn[t] = emb[(size_t)tnull[0] * En + t];
    __syncthreads();
#pragma unroll
    for (int hh = 0; hh < 2; hh++) {
        int h = t + hh * 256;
        float a = nnb[h];
        for (int e = 0; e < En; e++) a += xn[e] * nnW[(size_t)e * Hn + h];
        float v = tanhf(a);
        nsl[h] = v;
        if (blockIdx.x == 0) ns[h] = v;
    }
    __syncthreads();
    int v = blockIdx.x * 256 + t;
    float a = bv[v];
    for (int k = 0; k < Hn; k++) a += nsl[k] * Wv[(size_t)k * VS + v];
    float e = expf(a);
    for (int o = 1; o < 64; o <<= 1) e += __shfl_xor(e, o);
    if ((t & 63) == 0) red[t >> 6] = e;
    __syncthreads();
    if (t == 0) atomicAdd(nd, red[0] + red[1] + red[2] + red[3]);
}

// ---------------- persistent bidirectional LSTM ----------------
// 32 blocks x 256 threads. dir=blk>>4, u0=(blk&15)*32. Wh B-frags in LDS.
// h exchange: relaxed agent-scope bypass atomics (sc0 sc1 -> coherence point, no L2
// maintenance). Barrier: RELAXED flag store (no wbl2!) — ordering is provided by the
// vmcnt(0) drain inside __syncthreads before tid0 issues the flag store.
__global__ __launch_bounds__(256, 1) void lstm_persist_k(const float* __restrict__ wh_fw,
                                                         const float* __restrict__ wh_bw,
                                                         const float* __restrict__ gx,
                                                         const int* __restrict__ lengths,
                                                         unsigned* __restrict__ hbuf32,
                                                         unsigned* __restrict__ hcat32,
                                                         unsigned* __restrict__ slots) {
    __shared__ uint4 whf[8192];       // 128 KB B-frags
    __shared__ float raw[32][129];
    __shared__ int lenS[16];
    int tid = threadIdx.x;
    int blk = blockIdx.x;
    int dir = blk >> 4;
    int u0 = (blk & 15) * 32;
    const float* wh = dir ? wh_bw : wh_fw;
    if (tid < 16) lenS[tid] = lengths[tid];

    // one-time Wh -> bf16 B-frag staging
    for (int chunk = 0; chunk < 16; ++chunk) {
#pragma unroll
        for (int it = 0; it < 16; ++it) {
            int li = it * 256 + tid;
            int kl = li >> 7, c = li & 127;
            int g = c >> 5, ub = c & 31;
            raw[kl][c] = wh[(size_t)(chunk * 32 + kl) * 2048 + g * 512 + u0 + ub];
        }
        __syncthreads();
#pragma unroll
        for (int it = 0; it < 2; ++it) {
            int idx = tid * 2 + it;
            int w = idx >> 7, t = (idx >> 6) & 1, lane = idx & 63;
            int n = lane & 15, uu = n >> 1, p = n & 1;
            int cc = (t * 2 + p) * 32 + w * 8 + uu;
            int kb = (lane >> 4) * 8;
            unsigned short u8[8];
#pragma unroll
            for (int j = 0; j < 8; j++) u8[j] = tobf(raw[kb + j][cc]);
            whf[((w * 2 + t) * 16 + chunk) * 64 + lane] = *(uint4*)u8;
        }
        __syncthreads();
    }

    int wv = tid >> 6, lane = tid & 63;
    int n = lane & 15, uu = n >> 1, q = lane >> 4;
    int u = u0 + wv * 8 + uu;
    float creg[4] = {0.f, 0.f, 0.f, 0.f};
    unsigned short hbf[4] = {0, 0, 0, 0};

    for (int s = 0; s < 64; ++s) {
        // ---- gx prefetch (normal cached loads, issued first) ----
        float gxi[4], gxj[4], gxf[4], gxo[4];
#pragma unroll
        for (int r = 0; r < 4; r++) {
            int b = q * 4 + r;
            int len = lenS[b];
            int tc = dir ? (len - 1 - s) : s;
            tc = tc < 0 ? 0 : tc;
            const float* gp = gx + (size_t)dir * 2097152 + (size_t)(b * 64 + tc) * 2048 + u;
            gxi[r] = gp[0]; gxj[r] = gp[512]; gxf[r] = gp[1024]; gxo[r] = gp[1536];
        }
        // ---- A-frags: bypass-atomic u64 loads of h (b = n, k = units) ----
        const unsigned long long* hb64 =
            (const unsigned long long*)(hbuf32 + (((s & 1) * 2 + dir) * 16) * 256);
        unsigned long long h64[32];
#pragma unroll
        for (int ks = 0; ks < 16; ks++) {
            int idx = n * 128 + ks * 8 + q * 2;
            h64[2 * ks] = __hip_atomic_load(hb64 + idx, __ATOMIC_RELAXED, __HIP_MEMORY_SCOPE_AGENT);
            h64[2 * ks + 1] = __hip_atomic_load(hb64 + idx + 1, __ATOMIC_RELAXED, __HIP_MEMORY_SCOPE_AGENT);
        }
        // ---- MFMA ----
        f32x4 acc0 = {0.f, 0.f, 0.f, 0.f}, acc1 = {0.f, 0.f, 0.f, 0.f};
#pragma unroll
        for (int ks = 0; ks < 16; ks++) {
            unsigned long long av[2] = {h64[2 * ks], h64[2 * ks + 1]};
            short8 a = *reinterpret_cast<short8*>(av);
            uint4 b0 = whf[((wv * 2 + 0) * 16 + ks) * 64 + lane];
            uint4 b1 = whf[((wv * 2 + 1) * 16 + ks) * 64 + lane];
            acc0 = __builtin_amdgcn_mfma_f32_16x16x32_bf16(a, *reinterpret_cast<short8*>(&b0), acc0, 0, 0, 0);
            acc1 = __builtin_amdgcn_mfma_f32_16x16x32_bf16(a, *reinterpret_cast<short8*>(&b1), acc1, 0, 0, 0);
        }
        // ---- gates (even lanes i/f in acc0/acc1; odd lanes j/o of same unit) ----
#pragma unroll
        for (int r = 0; r < 4; r++) {
            float jvv = __shfl_xor(acc0[r], 1);
            float ovv = __shfl_xor(acc1[r], 1);
            int b = q * 4 + r;
            int len = lenS[b];
            float gi = acc0[r] + gxi[r];
            float gj = jvv + gxj[r];
            float gf = acc1[r] + gxf[r];
            float go = ovv + gxo[r];
            float cn = sigf(gf + 1.0f) * creg[r] + sigf(gi) * tanhf(gj);
            float hn = sigf(go) * tanhf(cn);
            if (s < len) { creg[r] = cn; hbf[r] = tobf(hn); }
        }
        // ---- pack unit pairs and store (lanes n%4==0 own units u,u+1) ----
#pragma unroll
        for (int r = 0; r < 4; r++) {
            unsigned self = hbf[r];
            unsigned part = (unsigned)__shfl_xor((int)self, 2) & 0xffffu;
            if ((n & 3) == 0) {
                unsigned pk = self | (part << 16);
                int b = q * 4 + r;
                __hip_atomic_store(
                    hbuf32 + ((((s + 1) & 1) * 2 + dir) * 16 + b) * 256 + (u >> 1), pk,
                    __ATOMIC_RELAXED, __HIP_MEMORY_SCOPE_AGENT);
                int len = lenS[b];
                if (s < len) {
                    int tin = dir ? (len - 1 - s) : s;
                    int row = b * 64 + tin, col = dir * 512 + u;
                    int mt = row >> 4, ksx = col >> 5;
                    int lanep = (row & 15) | (((col >> 3) & 3) << 4);
                    hcat32[(size_t)(((mt * 32 + ksx) * 64 + lanep) * 4) + ((col & 7) >> 1)] = pk;
                }
            }
        }
        if (s == 63) break;
        __syncthreads();  // vmcnt(0) drain: h stores at coherence point before flag
        if (tid == 0)     // RELAXED flag: no per-step buffer_wbl2
            __hip_atomic_store(&slots[blk * 64], (unsigned)(s + 1), __ATOMIC_RELAXED,
                               __HIP_MEMORY_SCOPE_AGENT);
        if (tid < 16) {
            while (__hip_atomic_load(&slots[(dir * 16 + tid) * 64], __ATOMIC_RELAXED,
                                     __HIP_MEMORY_SCOPE_AGENT) < (unsigned)(s + 1)) {
                __builtin_amdgcn_s_sleep(1);
            }
        }
        __syncthreads();
    }
}

// ---------------- Phase A: MFMA bf16 row-sum-of-exp ----------------
__global__ __launch_bounds__(256) void phaseA_mfma_k(const uint4* __restrict__ tsb,
                                                     const uint4* __restrict__ wvb,
                                                     const float* __restrict__ bv,
                                                     float* __restrict__ denom) {
    __shared__ float redL[4][128];
    int tid = threadIdx.x;
    int wave = tid >> 6, lane = tid & 63;
    int ntbase = blockIdx.x * 8 + wave * 2;
    float bv0 = bv[ntbase * 16 + (lane & 15)];
    float bv1 = bv[(ntbase + 1) * 16 + (lane & 15)];
    int q = lane >> 4;
    for (int mc = 0; mc < 8; ++mc) {
        f32x4 acc[8][2];
#pragma unroll
        for (int i = 0; i < 8; i++)
#pragma unroll
            for (int j = 0; j < 2; j++) acc[i][j] = 0.0f;
#pragma unroll 4
        for (int ks = 0; ks < 16; ++ks) {
            short8 a[8], b[2];
#pragma unroll
            for (int i = 0; i < 8; i++) {
                int mt = mc * 8 + i;
                uint4 t = tsb[(size_t)(mt * 16 + ks) * 64 + lane];
                a[i] = *reinterpret_cast<short8*>(&t);
            }
#pragma unroll
            for (int j = 0; j < 2; j++) {
                uint4 t = wvb[(size_t)((ntbase + j) * 16 + ks) * 64 + lane];
                b[j] = *reinterpret_cast<short8*>(&t);
            }
#pragma unroll
            for (int i = 0; i < 8; i++)
#pragma unroll
                for (int j = 0; j < 2; j++)
                    acc[i][j] = __builtin_amdgcn_mfma_f32_16x16x32_bf16(a[i], b[j], acc[i][j], 0, 0, 0);
        }
#pragma unroll
        for (int i = 0; i < 8; i++) {
#pragma unroll
            for (int r = 0; r < 4; r++) {
                float e = __expf(acc[i][0][r] + bv0) + __expf(acc[i][1][r] + bv1);
                e += __shfl_xor(e, 1);
                e += __shfl_xor(e, 2);
                e += __shfl_xor(e, 4);
                e += __shfl_xor(e, 8);
                if ((lane & 15) == 0) redL[wave][i * 16 + q * 4 + r] = e;
            }
        }
        __syncthreads();
        if (tid < 128) {
            float v = redL[0][tid] + redL[1][tid] + redL[2][tid] + redL[3][tid];
            atomicAdd(&denom[mc * 128 + tid], v);
        }
        __syncthreads();
    }
}

// ---------------- emission assembly ----------------
__global__ __launch_bounds__(512) void emission_k(const float* __restrict__ ts,
                                                  const float* __restrict__ Wv,
                                                  const float* __restrict__ bv,
                                                  const int* __restrict__ sources,
                                                  const float* __restrict__ ns,
                                                  const float* __restrict__ denom,
                                                  const float* __restrict__ nulld,
                                                  float* __restrict__ em) {
    __shared__ float colv[512];
    __shared__ float red[64][9];
    __shared__ float red2[8];
    __shared__ float env_s, bvc_s;
    int b = blockIdx.y, sc = blockIdx.x;
    int tid = threadIdx.x;
    for (int qq = 0; qq < 8; ++qq) {
        int s = sc * 8 + qq;
        int c = sources[b * 64 + s];
        __syncthreads();
        colv[tid] = Wv[(size_t)tid * VS + c];
        if (tid == 0) bvc_s = bv[c];
        __syncthreads();
        int r = tid & 63, ksl = tid >> 6;
        const float* tr = ts + (size_t)(b * 64 + r) * 512 + ksl * 64;
        float p = 0.f;
#pragma unroll
        for (int k4 = 0; k4 < 16; k4++) {
            float4 t4 = *(const float4*)(tr + k4 * 4);
            float4 c4 = *(const float4*)&colv[ksl * 64 + k4 * 4];
            p += t4.x * c4.x + t4.y * c4.y + t4.z * c4.z + t4.w * c4.w;
        }
        red[r][ksl] = p;
        if (tid < 8) {
            float pn = 0.f;
#pragma unroll
            for (int k4 = 0; k4 < 16; k4++) {
                float4 n4 = *(const float4*)(ns + tid * 64 + k4 * 4);
                float4 c4 = *(const float4*)&colv[tid * 64 + k4 * 4];
                pn += n4.x * c4.x + n4.y * c4.y + n4.z * c4.z + n4.w * c4.w;
            }
            red2[tid] = pn;
        }
        __syncthreads();
        if (tid < 64) {
            float dot = red[tid][0] + red[tid][1] + red[tid][2] + red[tid][3] +
                        red[tid][4] + red[tid][5] + red[tid][6] + red[tid][7];
            float ew = expf(dot + bvc_s) / denom[b * 64 + tid];
            em[(size_t)(b * 128 + tid) * 64 + s] = ew;
        } else if (tid == 64) {
            float dn = red2[0] + red2[1] + red2[2] + red2[3] +
                       red2[4] + red2[5] + red2[6] + red2[7];
            env_s = expf(dn + bvc_s) / nulld[0];
        }
        __syncthreads();
        if (tid < 64) em[(size_t)(b * 128 + 64 + tid) * 64 + s] = env_s;
    }
}

// ---------------- transition ----------------
__global__ __launch_bounds__(256) void transition_k(const float* __restrict__ tt,
                                                    const float* __restrict__ Wj,
                                                    const float* __restrict__ bj,
                                                    const float* __restrict__ Wp0,
                                                    const float* __restrict__ bp0,
                                                    float* __restrict__ trans,
                                                    float* __restrict__ tlog) {
    __shared__ float ttl[512];
    __shared__ float jrow[Jn], ljrow[Jn];
    __shared__ float sred[256];
    __shared__ float p0_s, lp0_s;
    int blk = blockIdx.x;
    int b = blk >> 6, i = blk & 63;
    int tid = threadIdx.x;
    {
        const float* trr = tt + (size_t)blk * 512;
        if (tid < 128) *(float4*)&ttl[tid * 4] = *(const float4*)(trr + tid * 4);
    }
    __syncthreads();
    bool isj = tid < Jn;
    bool isp = tid == Jn;
    float l = 0.f;
    if (isj || isp) {
        const float* wb = isj ? (Wj + tid) : Wp0;
        int stride = isj ? Jn : 1;
        float a = isj ? bj[tid] : bp0[0];
        for (int k = 0; k < 512; k++) a += ttl[k] * wb[(size_t)k * stride];
        l = a;
    }
    sred[tid] = isj ? l : -1e30f;
    __syncthreads();
    for (int o = 128; o > 0; o >>= 1) {
        if (tid < o) sred[tid] = fmaxf(sred[tid], sred[tid + o]);
        __syncthreads();
    }
    float m = sred[0];
    __syncthreads();
    float ex = isj ? expf(l - m) : 0.f;
    sred[tid] = ex;
    __syncthreads();
    for (int o = 128; o > 0; o >>= 1) {
        if (tid < o) sred[tid] += sred[tid + o];
        __syncthreads();
    }
    float S = sred[0];
    if (isj) {
        jrow[tid] = ex / S;
        ljrow[tid] = (l - m) - logf(S);
    }
    if (isp) {
        float pv = 1.f / (1.f + expf(-l));
        p0_s = pv;
        lp0_s = logf(pv);
    }
    __syncthreads();
    if (tid < 128) {
        int j = tid;
        float tv, lv;
        if (j < 64) {
            int id = Mn + j - i;
            tv = jrow[id];
            lv = ljrow[id];
        } else {
            bool dg = (j - 64) == i;
            tv = dg ? p0_s : 0.f;
            lv = dg ? lp0_s : 0.f;
        }
        size_t r1 = (size_t)(b * 128 + i) * 128 + j;
        size_t r2 = (size_t)(b * 128 + 64 + i) * 128 + j;
        trans[r1] = tv;
        trans[r2] = tv;
        tlog[r1] = lv;
        tlog[r2] = lv;
    }
}

extern "C" void kernel_launch(void* const* d_in, const int* in_sizes, int n_in,
                              void* d_out, int out_size, void* d_ws, size_t ws_size,
                              hipStream_t stream) {
    const int* sources = (const int*)d_in[0];
    const int* targets = (const int*)d_in[1];
    const int* tnull = (const int*)d_in[2];
    const int* lengths = (const int*)d_in[3];
    const float* emb = (const float*)d_in[4];
    const float* nnW = (const float*)d_in[5];
    const float* nnb = (const float*)d_in[6];
    const float* Wx_fw = (const float*)d_in[7];
    const float* Wh_fw = (const float*)d_in[8];
    const float* b_fw = (const float*)d_in[9];
    const float* Wx_bw = (const float*)d_in[10];
    const float* Wh_bw = (const float*)d_in[11];
    const float* b_bw = (const float*)d_in[12];
    const float* Wproj_e = (const float*)d_in[13];
    const float* Wv = (const float*)d_in[14];
    const float* bv = (const float*)d_in[15];
    const float* Wproj_t = (const float*)d_in[16];
    const float* Wj = (const float*)d_in[17];
    const float* bj = (const float*)d_in[18];
    const float* Wp0 = (const float*)d_in[19];
    const float* bp0 = (const float*)d_in[20];

    float* ws = (float*)d_ws;
    float* out = (float*)d_out;
    float* out_em = out;                     // [16][128][64]
    float* out_tr = out + 131072;            // [16][128][128]
    float* out_tl = out + 131072 + 262144;   // [16][128][128]

    // 1) fused zero + all input-side bf16 fragment converts (one launch)
    mega_prep_k<<<1636, 256, 0, stream>>>((float4*)ws, ZERO_N / 4,
                                          emb, targets, (uint4*)(ws + O_XF),
                                          Wx_fw, (uint4*)(ws + O_WXFW),
                                          Wx_bw, (uint4*)(ws + O_WXBW),
                                          Wproj_e, (uint4*)(ws + O_WPEF),
                                          Wproj_t, (uint4*)(ws + O_WPTF),
                                          nnW, (uint4*)(ws + O_NNWF));

    // 2) gx = gather(emb,targets) @ Wx + b  (MFMA)
    gemm_mfma_k<0><<<dim3(16, 8), 256, 0, stream>>>((uint4*)(ws + O_XF), (uint4*)(ws + O_WXFW),
                                                    b_fw, ws + O_GX, 2048, 8);
    gemm_mfma_k<0><<<dim3(16, 8), 256, 0, stream>>>((uint4*)(ws + O_XF), (uint4*)(ws + O_WXBW),
                                                    b_bw, ws + O_GX + 2097152, 2048, 8);

    // 3) fused null state + denominator
    null_fused_k<<<125, 256, 0, stream>>>(emb, tnull, nnW, nnb, Wv, bv,
                                          ws + O_NS, ws + O_NULLD);

    // 4) persistent bidirectional LSTM
    lstm_persist_k<<<32, 256, 0, stream>>>(Wh_fw, Wh_bw, ws + O_GX, lengths,
                                           (unsigned*)(ws + O_HBUF), (unsigned*)(ws + O_HCATF),
                                           (unsigned*)(ws + O_SLOTS));

    // 5) projections (MFMA on hcat frags)
    gemm_mfma_k<0><<<dim3(4, 8), 256, 0, stream>>>((uint4*)(ws + O_HCATF), (uint4*)(ws + O_WPEF),
                                                   nullptr, ws + O_TS, 512, 32);
    gemm_mfma_k<0><<<dim3(2, 8), 256, 0, stream>>>((uint4*)(ws + O_HCATF), (uint4*)(ws + O_WPTF),
                                                   nullptr, ws + O_TTPRE, 256, 32);
    convA_k<<<128, 256, 0, stream>>>(ws + O_TTPRE, (uint4*)(ws + O_TTPF), 256, nullptr);
    gemm_mfma_k<1><<<dim3(4, 8), 256, 0, stream>>>((uint4*)(ws + O_TTPF), (uint4*)(ws + O_NNWF),
                                                   nnb, ws + O_TT, 512, 8);
    convA_k<<<256, 256, 0, stream>>>(ws + O_TS, (uint4*)(ws + O_TSF), 512, nullptr);

    // 6) Wv -> B-frags (overlays gx region, dead now), then phase A
    convB_k<<<8000, 256, 0, stream>>>(Wv, (uint4*)(ws + O_WVB), VS, 512);
    phaseA_mfma_k<<<250, 256, 0, stream>>>((const uint4*)(ws + O_TSF),
                                           (const uint4*)(ws + O_WVB), bv, ws + O_DENOM);

    // 7) emission output
    emission_k<<<dim3(8, 16), 512, 0, stream>>>(ws + O_TS, Wv, bv, sources, ws + O_NS,
                                                ws + O_DENOM, ws + O_NULLD, out_em);

    // 8) transition outputs
    transition_k<<<1024, 256, 0, stream>>>(ws + O_TT, Wj, bj, Wp0, bp0, out_tr, out_tl);
}